// Round 2
// baseline (253.259 us; speedup 1.0000x reference)
//
#include <hip/hip_runtime.h>
#include <math.h>

#define N_NODES 50000
#define N_EDGES 800000
#define IN_CH   256
#define OUT_CH  64
#define HEADS   4
#define NEG_SLOPE 0.2f
#define NCOLS   320           // W (256) || W_res (64)
#define NTILES  20            // NCOLS / 16
#define NKK     8             // IN_CH / 32
#define PACK_BLOCKS 40        // NKK*NTILES*64 / 256
#define GEMM_BLOCKS 782       // (N_NODES+63)/64
#define SCAN_BLOCKS 196       // (N_NODES+255)/256
#define HIST_BLOCKS 3125      // N_EDGES/256
#define SCAT_BLOCKS 3125      // N_EDGES/256
#define AGG_BLOCKS  6250      // half of N_NODES/4; launched twice (diagnostic split)

typedef __attribute__((ext_vector_type(8))) short short8;
typedef __attribute__((ext_vector_type(4))) float f32x4;

__device__ __forceinline__ float lrelu(float v) {
    return v > 0.f ? v : NEG_SLOPE * v;
}
__device__ __forceinline__ unsigned bf16_rne(float f) {
    unsigned u = __float_as_uint(f);
    return (u + 0x7FFFu + ((u >> 16) & 1u)) >> 16;
}
__device__ __forceinline__ unsigned pack2(float lo, float hi) {
    return bf16_rne(lo) | (bf16_rne(hi) << 16);
}
__device__ __forceinline__ float bflo(unsigned u) { return __uint_as_float(u << 16); }
__device__ __forceinline__ float bfhi(unsigned u) { return __uint_as_float(u & 0xFFFF0000u); }
__device__ __forceinline__ short8 as_short8(uint4 u) {
    union { uint4 u4; short8 s8; } cv; cv.u4 = u; return cv.s8;
}

// ---------------------------------------------------------------------------
// pack_B: [W | W_res] fp32 -> bf16 MFMA B-fragment order (tiny, 40 blocks).
// ---------------------------------------------------------------------------
__global__ __launch_bounds__(256) void pack_B(
    const float* __restrict__ W, const float* __restrict__ Wres,
    uint4* __restrict__ Bp)
{
    const int idx  = blockIdx.x * 256 + threadIdx.x;   // 0..10239
    const int kk   = idx / (NTILES * 64);
    const int rem  = idx - kk * (NTILES * 64);
    const int t    = rem >> 6;
    const int lane = rem & 63;
    const int colL = lane & 15, quad = lane >> 4;
    const int col  = t * 16 + colL;
    const int k0   = kk * 32 + quad * 8;
    float v[8];
    #pragma unroll
    for (int j = 0; j < 8; ++j) {
        const int k = k0 + j;
        v[j] = (col < IN_CH) ? W[(size_t)k * IN_CH + col]
                             : Wres[(size_t)k * OUT_CH + (col - IN_CH)];
    }
    uint4 u;
    u.x = pack2(v[0], v[1]); u.y = pack2(v[2], v[3]);
    u.z = pack2(v[4], v[5]); u.w = pack2(v[6], v[7]);
    Bp[(kk * NTILES + t) * 64 + lane] = u;
}

// ---------------------------------------------------------------------------
// hist_gemm: fused independent halves.
//   blocks [0, GEMM_BLOCKS)          : MFMA node transform + FUSED LOGITS
//   blocks [GEMM_BLOCKS,+HIST_BLOCKS): histogram with POSITION CAPTURE —
//     epos[e] = atomicAdd(&cnt[d],1).
// gemm: wave wv owns col-tiles {wv,4+wv,8+wv,12+wv,16+wv} over 4 row-groups;
// C/D: col=lane&15, row=(lane>>4)*4+reg. xw2 uint2 = (h0,h1|h2,h3) bf16.
// R2: attention logits a_src/a_dst computed HERE from fp32 acc (wave already
// holds xw in registers) — removes the 25.6 MB xw2 re-read and the whole
// 12500-block logits half of the old scatter_logits kernel. Per (rg,h,r):
// 16-lane shfl_xor dot over this wave's 16 channels, LDS float atomics to
// combine the 4 waves' channel slices, coalesced write of [64 rows][4 h].
// More accurate than before (fp32 acc, not bf16-rounded xw2).
// ---------------------------------------------------------------------------
__global__ __launch_bounds__(256) void hist_gemm(
    const float* __restrict__ x, const uint4* __restrict__ Bp,
    uint2* __restrict__ xw2, float* __restrict__ xres,
    const int* __restrict__ ei, int* __restrict__ cnt,
    int* __restrict__ epos,
    const float* __restrict__ attS, const float* __restrict__ attD,
    float* __restrict__ asrc, float* __restrict__ adst)
{
    __shared__ uint4 Alds[4 * NKK * 64];   // 32 KB
    __shared__ float logS[64][HEADS];      // 1 KB
    __shared__ float logD[64][HEADS];      // 1 KB

    if (blockIdx.x >= GEMM_BLOCKS) {
        const int e = (blockIdx.x - GEMM_BLOCKS) * 256 + threadIdx.x;
        if (e < N_EDGES)
            epos[e] = atomicAdd(&cnt[ei[N_EDGES + e]], 1);
        return;
    }

    const int tid = threadIdx.x;
    const int n0  = blockIdx.x * 64;

    // zero the logit accumulators (256 threads == 64*4 entries)
    logS[tid >> 2][tid & 3] = 0.f;
    logD[tid >> 2][tid & 3] = 0.f;

    #pragma unroll
    for (int i = 0; i < 8; ++i) {
        const int e    = i * 256 + tid;
        const int g    = e >> 9;
        const int kk   = (e >> 6) & 7;
        const int lane = e & 63;
        const int cL   = lane & 15, qd = lane >> 4;
        const int row  = n0 + g * 16 + cL;
        const int k0   = kk * 32 + qd * 8;
        uint4 u = make_uint4(0u, 0u, 0u, 0u);
        if (row < N_NODES) {
            const float4 a = *reinterpret_cast<const float4*>(x + (size_t)row * IN_CH + k0);
            const float4 b = *reinterpret_cast<const float4*>(x + (size_t)row * IN_CH + k0 + 4);
            u.x = pack2(a.x, a.y); u.y = pack2(a.z, a.w);
            u.z = pack2(b.x, b.y); u.w = pack2(b.z, b.w);
        }
        Alds[(g * NKK + kk) * 64 + lane] = u;
    }
    __syncthreads();

    const int lane = tid & 63;
    const int wv   = tid >> 6;
    const int colL = lane & 15, quad = lane >> 4;

    f32x4 acc[4][5];
    #pragma unroll
    for (int rg = 0; rg < 4; ++rg)
        #pragma unroll
        for (int j = 0; j < 5; ++j) acc[rg][j] = (f32x4){0.f, 0.f, 0.f, 0.f};

    for (int kk = 0; kk < NKK; ++kk) {
        uint4 bu[5];
        #pragma unroll
        for (int j = 0; j < 5; ++j)
            bu[j] = Bp[(kk * NTILES + j * 4 + wv) * 64 + lane];
        #pragma unroll
        for (int rg = 0; rg < 4; ++rg) {
            const short8 a = as_short8(Alds[(rg * NKK + kk) * 64 + lane]);
            #pragma unroll
            for (int j = 0; j < 5; ++j)
                acc[rg][j] = __builtin_amdgcn_mfma_f32_16x16x32_bf16(
                    a, as_short8(bu[j]), acc[rg][j], 0, 0, 0);
        }
    }

    // ---- store xw2 / xres (unchanged) ----
    #pragma unroll
    for (int rg = 0; rg < 4; ++rg) {
        #pragma unroll
        for (int r = 0; r < 4; ++r) {
            const int row = n0 + rg * 16 + quad * 4 + r;
            if (row < N_NODES) {
                xw2[(size_t)row * 64 + wv * 16 + colL] = make_uint2(
                    pack2(acc[rg][0][r], acc[rg][1][r]),
                    pack2(acc[rg][2][r], acc[rg][3][r]));
                xres[(size_t)row * OUT_CH + wv * 16 + colL] = acc[rg][4][r];
            }
        }
    }

    // ---- fused logits ----
    // this wave's channel slice within each head: c = wv*16 + colL
    float aSr[HEADS], aDr[HEADS];
    #pragma unroll
    for (int h = 0; h < HEADS; ++h) {
        aSr[h] = attS[h * 64 + wv * 16 + colL];
        aDr[h] = attD[h * 64 + wv * 16 + colL];
    }
    #pragma unroll
    for (int rg = 0; rg < 4; ++rg) {
        #pragma unroll
        for (int h = 0; h < HEADS; ++h) {
            #pragma unroll
            for (int r = 0; r < 4; ++r) {
                float vS = acc[rg][h][r] * aSr[h];
                float vD = acc[rg][h][r] * aDr[h];
                #pragma unroll
                for (int m = 1; m < 16; m <<= 1) {      // stays within quad
                    vS += __shfl_xor(vS, m);
                    vD += __shfl_xor(vD, m);
                }
                if (colL == 0) {
                    atomicAdd(&logS[rg * 16 + quad * 4 + r][h], vS);
                    atomicAdd(&logD[rg * 16 + quad * 4 + r][h], vD);
                }
            }
        }
    }
    __syncthreads();
    {
        const int rl = tid >> 2, h = tid & 3;
        const int row = n0 + rl;
        if (row < N_NODES) {
            asrc[(size_t)row * HEADS + h] = logS[rl][h];
            adst[(size_t)row * HEADS + h] = logD[rl][h];
        }
    }
}

// ---------------------------------------------------------------------------
// scan_local: per-256-chunk exclusive scan of cnt; block sums to bsum.
// Consumers inline the 196-element bsum scan (L2-hot).
// ---------------------------------------------------------------------------
__global__ __launch_bounds__(256) void scan_local(
    const int* __restrict__ cnt, int* __restrict__ lscan, int* __restrict__ bsum)
{
    __shared__ int ws[4];
    const int t = threadIdx.x, lane = t & 63, w = t >> 6;
    const int i = blockIdx.x * 256 + t;
    const int v = (i < N_NODES) ? cnt[i] : 0;
    int sc = v;
    #pragma unroll
    for (int off = 1; off < 64; off <<= 1) {
        const int n = __shfl_up(sc, off);
        if (lane >= off) sc += n;
    }
    if (lane == 63) ws[w] = sc;
    __syncthreads();
    int prefix = 0;
    for (int j = 0; j < w; ++j) prefix += ws[j];
    if (i < N_NODES) lscan[i] = prefix + sc - v;
    if (t == 255) bsum[blockIdx.x] = prefix + sc;
}

// ---------------------------------------------------------------------------
// scatter_edges: ATOMIC-FREE scatter — slot comes from epos[e] captured
// during the histogram. Coalesced reads + one random 4 B write per edge.
// (logits half moved into hist_gemm epilogue in R2)
// ---------------------------------------------------------------------------
__global__ __launch_bounds__(256) void scatter_edges(
    const int* __restrict__ ei, const int* __restrict__ epos,
    const int* __restrict__ lscan, const int* __restrict__ bsum,
    int* __restrict__ esrc)
{
    __shared__ int bsx[256];
    __shared__ int ws[4];
    const int t = threadIdx.x;
    const int lane = t & 63, wv = t >> 6;

    const int v = (t < SCAN_BLOCKS) ? bsum[t] : 0;
    int sc = v;
    #pragma unroll
    for (int off = 1; off < 64; off <<= 1) {
        const int n = __shfl_up(sc, off);
        if (lane >= off) sc += n;
    }
    if (lane == 63) ws[wv] = sc;
    __syncthreads();
    int prefix = 0;
    for (int j = 0; j < wv; ++j) prefix += ws[j];
    bsx[t] = prefix + sc - v;
    __syncthreads();

    const int e = blockIdx.x * 256 + t;
    if (e < N_EDGES) {
        const int d = ei[N_EDGES + e];
        esrc[lscan[d] + bsx[d >> 8] + epos[e]] = ei[e];
    }
}

// ---------------------------------------------------------------------------
// aggregate, single-pass, unnormalized head accumulators. Inline bsum scan.
// Per 64-edge chunk: lane-parallel gather asrc + exp -> LDS stash; per edge:
// uniform-addr LDS broadcast + ONE dwordx2 gather + 4 fma. 4x unroll, live
// regs kept low (latency-bound: occupancy > ILP — R6 lesson).
// R2: launched as TWO half-grid dispatches (d0 = 0 / 25000) purely so the
// rocprof top-5 stops being 5 aggregate replicas and exposes the other
// kernels' counters. R1 established aggregate is at its structural floor:
// 214 MB = 8 XCD x 25.6 MB compulsory L2 streaming at ~3.3 TB/s (MSHR-bound;
// extra wave-level MLP was a measured no-op).
// ---------------------------------------------------------------------------
__global__ __launch_bounds__(256) void aggregate(
    const int* __restrict__ esrc, const int* __restrict__ lscan,
    const int* __restrict__ bsum, const int* __restrict__ cnt,
    const float* __restrict__ asrc, const float* __restrict__ adst,
    const uint2* __restrict__ xw2, const float* __restrict__ xres,
    const float* __restrict__ bias, float* __restrict__ out,
    const int d0)
{
    __shared__ float4 wbuf[4][64];
    __shared__ int    sbuf[4][64];
    __shared__ int    bsx[256];
    __shared__ int    ws[4];
    const int t = threadIdx.x;
    const int lane = t & 63;
    const int wv   = t >> 6;

    {
        const int v = (t < SCAN_BLOCKS) ? bsum[t] : 0;
        int sc = v;
        #pragma unroll
        for (int off = 1; off < 64; off <<= 1) {
            const int n = __shfl_up(sc, off);
            if (lane >= off) sc += n;
        }
        if (lane == 63) ws[wv] = sc;
        __syncthreads();
        int prefix = 0;
        for (int j = 0; j < wv; ++j) prefix += ws[j];
        bsx[t] = prefix + sc - v;
        __syncthreads();
    }

    const int d = d0 + blockIdx.x * 4 + wv;
    const int row = lscan[d] + bsx[d >> 8];
    const int deg = cnt[d];
    const float4 ad = *reinterpret_cast<const float4*>(adst + (size_t)d * 4);
    const char* xwB = (const char*)xw2;
    const int laneB = lane << 3;

    float dn0 = 0.f, dn1 = 0.f, dn2 = 0.f, dn3 = 0.f;
    float ac0 = 0.f, ac1 = 0.f, ac2 = 0.f, ac3 = 0.f;

    for (int base = 0; base < deg; base += 64) {
        const int m = min(64, deg - base);
        if (lane < m) {
            const int s = esrc[row + base + lane];
            const float4 as = *reinterpret_cast<const float4*>(asrc + (size_t)s * 4);
            const float e0 = __expf(lrelu(as.x + ad.x));
            const float e1 = __expf(lrelu(as.y + ad.y));
            const float e2 = __expf(lrelu(as.z + ad.z));
            const float e3 = __expf(lrelu(as.w + ad.w));
            dn0 += e0; dn1 += e1; dn2 += e2; dn3 += e3;
            wbuf[wv][lane] = make_float4(e0, e1, e2, e3);
            sbuf[wv][lane] = s << 9;   // *512 B node row
        }
        int j = 0;
        for (; j + 4 <= m; j += 4) {
            uint2 v0 = *(const uint2*)(xwB + sbuf[wv][j]     + laneB);
            uint2 v1 = *(const uint2*)(xwB + sbuf[wv][j + 1] + laneB);
            uint2 v2 = *(const uint2*)(xwB + sbuf[wv][j + 2] + laneB);
            uint2 v3 = *(const uint2*)(xwB + sbuf[wv][j + 3] + laneB);
            {
                const float4 w = wbuf[wv][j];
                ac0 = fmaf(w.x, bflo(v0.x), ac0); ac1 = fmaf(w.y, bfhi(v0.x), ac1);
                ac2 = fmaf(w.z, bflo(v0.y), ac2); ac3 = fmaf(w.w, bfhi(v0.y), ac3);
            }
            {
                const float4 w = wbuf[wv][j + 1];
                ac0 = fmaf(w.x, bflo(v1.x), ac0); ac1 = fmaf(w.y, bfhi(v1.x), ac1);
                ac2 = fmaf(w.z, bflo(v1.y), ac2); ac3 = fmaf(w.w, bfhi(v1.y), ac3);
            }
            {
                const float4 w = wbuf[wv][j + 2];
                ac0 = fmaf(w.x, bflo(v2.x), ac0); ac1 = fmaf(w.y, bfhi(v2.x), ac1);
                ac2 = fmaf(w.z, bflo(v2.y), ac2); ac3 = fmaf(w.w, bfhi(v2.y), ac3);
            }
            {
                const float4 w = wbuf[wv][j + 3];
                ac0 = fmaf(w.x, bflo(v3.x), ac0); ac1 = fmaf(w.y, bfhi(v3.x), ac1);
                ac2 = fmaf(w.z, bflo(v3.y), ac2); ac3 = fmaf(w.w, bfhi(v3.y), ac3);
            }
        }
        for (; j < m; ++j) {
            const float4 w = wbuf[wv][j];
            const uint2 v = *(const uint2*)(xwB + sbuf[wv][j] + laneB);
            ac0 = fmaf(w.x, bflo(v.x), ac0);
            ac1 = fmaf(w.y, bfhi(v.x), ac1);
            ac2 = fmaf(w.z, bflo(v.y), ac2);
            ac3 = fmaf(w.w, bfhi(v.y), ac3);
        }
    }

    #pragma unroll
    for (int off = 32; off >= 1; off >>= 1) {
        dn0 += __shfl_xor(dn0, off);
        dn1 += __shfl_xor(dn1, off);
        dn2 += __shfl_xor(dn2, off);
        dn3 += __shfl_xor(dn3, off);
    }
    // self-loop
    const float4 asd = *reinterpret_cast<const float4*>(asrc + (size_t)d * 4);
    const float s0 = __expf(lrelu(asd.x + ad.x));
    const float s1 = __expf(lrelu(asd.y + ad.y));
    const float s2 = __expf(lrelu(asd.z + ad.z));
    const float s3 = __expf(lrelu(asd.w + ad.w));
    const uint2 u = xw2[(size_t)d * 64 + lane];
    ac0 = fmaf(s0, bflo(u.x), ac0); ac1 = fmaf(s1, bfhi(u.x), ac1);
    ac2 = fmaf(s2, bflo(u.y), ac2); ac3 = fmaf(s3, bfhi(u.y), ac3);
    const float i0 = 0.25f / (dn0 + s0);
    const float i1 = 0.25f / (dn1 + s1);
    const float i2 = 0.25f / (dn2 + s2);
    const float i3 = 0.25f / (dn3 + s3);
    const float v = ac0 * i0 + ac1 * i1 + ac2 * i2 + ac3 * i3
                  + bias[lane] + xres[(size_t)d * OUT_CH + lane];
    out[(size_t)d * OUT_CH + lane] = fmaxf(v, 0.f);
}

extern "C" void kernel_launch(void* const* d_in, const int* in_sizes, int n_in,
                              void* d_out, int out_size, void* d_ws, size_t ws_size,
                              hipStream_t stream) {
    const float* x    = (const float*)d_in[0];
    const int*   ei   = (const int*)d_in[1];
    const float* W    = (const float*)d_in[2];
    const float* attS = (const float*)d_in[3];
    const float* attD = (const float*)d_in[4];
    const float* bias = (const float*)d_in[5];
    const float* Wres = (const float*)d_in[6];
    float* out = (float*)d_out;

    char* p = (char*)d_ws;
    uint4*    Bp    = (uint4*)p;    p += (size_t)NKK * NTILES * 64 * 16;  // 160 KB
    uint2*    xw2   = (uint2*)p;    p += (size_t)N_NODES * 64 * 8;        // 25.6 MB
    float*    xres  = (float*)p;    p += (size_t)N_NODES * OUT_CH * 4;    // 12.8 MB
    float*    asrc  = (float*)p;    p += (size_t)N_NODES * HEADS * 4;
    float*    adst  = (float*)p;    p += (size_t)N_NODES * HEADS * 4;
    int*      cnt   = (int*)p;      p += (size_t)N_NODES * 4;
    int*      lscan = (int*)p;      p += (size_t)N_NODES * 4;
    int*      bsum  = (int*)p;      p += 256 * 4;
    int*      epos  = (int*)p;      p += (size_t)N_EDGES * 4;
    int*      esrc  = (int*)p;      p += (size_t)N_EDGES * 4;

    hipMemsetAsync(cnt, 0, (size_t)N_NODES * sizeof(int), stream);

    pack_B<<<PACK_BLOCKS, 256, 0, stream>>>(W, Wres, Bp);
    hist_gemm<<<GEMM_BLOCKS + HIST_BLOCKS, 256, 0, stream>>>(
        x, Bp, xw2, xres, ei, cnt, epos, attS, attD, asrc, adst);
    scan_local<<<SCAN_BLOCKS, 256, 0, stream>>>(cnt, lscan, bsum);
    scatter_edges<<<SCAT_BLOCKS, 256, 0, stream>>>(
        ei, epos, lscan, bsum, esrc);
    aggregate<<<AGG_BLOCKS, 256, 0, stream>>>(
        esrc, lscan, bsum, cnt, asrc, adst, xw2, xres, bias, out, 0);
    aggregate<<<AGG_BLOCKS, 256, 0, stream>>>(
        esrc, lscan, bsum, cnt, asrc, adst, xw2, xres, bias, out, 25000);
}

// Round 3
// 248.433 us; speedup vs baseline: 1.0194x; 1.0194x over previous
//
#include <hip/hip_runtime.h>
#include <math.h>

#define N_NODES 50000
#define N_EDGES 800000
#define IN_CH   256
#define OUT_CH  64
#define HEADS   4
#define NEG_SLOPE 0.2f
#define NCOLS   320           // W (256) || W_res (64)
#define NTILES  20            // NCOLS / 16
#define NKK     8             // IN_CH / 32
#define PACK_BLOCKS 40        // NKK*NTILES*64 / 256
#define GEMM_BLOCKS 782       // (N_NODES+63)/64
#define SCAN_BLOCKS 196       // (N_NODES+255)/256
#define HIST_BLOCKS 3125      // N_EDGES/256
#define SCAT_BLOCKS 3125      // N_EDGES/256
#define AGG_BLOCKS  6250      // half of N_NODES/4; launched twice (diagnostic split)
// R3: cnt padded to ONE COUNTER PER 64B LINE. 800k device atomics into 3125
// lines (256/line) serialized at ~0.3us/line-op = the measured 75us. 16x
// fewer ops/line -> histogram drains in ~5us.
#define CNT_SHIFT 4           // stride 16 ints = 64 B

typedef __attribute__((ext_vector_type(8))) short short8;
typedef __attribute__((ext_vector_type(4))) float f32x4;

__device__ __forceinline__ float lrelu(float v) {
    return v > 0.f ? v : NEG_SLOPE * v;
}
__device__ __forceinline__ unsigned bf16_rne(float f) {
    unsigned u = __float_as_uint(f);
    return (u + 0x7FFFu + ((u >> 16) & 1u)) >> 16;
}
__device__ __forceinline__ unsigned pack2(float lo, float hi) {
    return bf16_rne(lo) | (bf16_rne(hi) << 16);
}
__device__ __forceinline__ float bflo(unsigned u) { return __uint_as_float(u << 16); }
__device__ __forceinline__ float bfhi(unsigned u) { return __uint_as_float(u & 0xFFFF0000u); }
__device__ __forceinline__ short8 as_short8(uint4 u) {
    union { uint4 u4; short8 s8; } cv; cv.u4 = u; return cv.s8;
}

// ---------------------------------------------------------------------------
// pack_B: [W | W_res] fp32 -> bf16 MFMA B-fragment order (tiny, 40 blocks).
// ---------------------------------------------------------------------------
__global__ __launch_bounds__(256) void pack_B(
    const float* __restrict__ W, const float* __restrict__ Wres,
    uint4* __restrict__ Bp)
{
    const int idx  = blockIdx.x * 256 + threadIdx.x;   // 0..10239
    const int kk   = idx / (NTILES * 64);
    const int rem  = idx - kk * (NTILES * 64);
    const int t    = rem >> 6;
    const int lane = rem & 63;
    const int colL = lane & 15, quad = lane >> 4;
    const int col  = t * 16 + colL;
    const int k0   = kk * 32 + quad * 8;
    float v[8];
    #pragma unroll
    for (int j = 0; j < 8; ++j) {
        const int k = k0 + j;
        v[j] = (col < IN_CH) ? W[(size_t)k * IN_CH + col]
                             : Wres[(size_t)k * OUT_CH + (col - IN_CH)];
    }
    uint4 u;
    u.x = pack2(v[0], v[1]); u.y = pack2(v[2], v[3]);
    u.z = pack2(v[4], v[5]); u.w = pack2(v[6], v[7]);
    Bp[(kk * NTILES + t) * 64 + lane] = u;
}

// ---------------------------------------------------------------------------
// hist_gemm: fused independent halves.
//   blocks [0, GEMM_BLOCKS)          : MFMA node transform + FUSED LOGITS
//   blocks [GEMM_BLOCKS,+HIST_BLOCKS): histogram with POSITION CAPTURE —
//     epos[e] = atomicAdd(&cnt[d<<CNT_SHIFT],1). Padded counters (R3): one
//     per 64B line, killing the per-line atomic serialization that made the
//     histogram the 75us long pole.
// gemm: wave wv owns col-tiles {wv,4+wv,8+wv,12+wv,16+wv} over 4 row-groups;
// C/D: col=lane&15, row=(lane>>4)*4+reg. xw2 uint2 = (h0,h1|h2,h3) bf16.
// ---------------------------------------------------------------------------
__global__ __launch_bounds__(256) void hist_gemm(
    const float* __restrict__ x, const uint4* __restrict__ Bp,
    uint2* __restrict__ xw2, float* __restrict__ xres,
    const int* __restrict__ ei, int* __restrict__ cnt,
    int* __restrict__ epos,
    const float* __restrict__ attS, const float* __restrict__ attD,
    float* __restrict__ asrc, float* __restrict__ adst)
{
    __shared__ uint4 Alds[4 * NKK * 64];   // 32 KB
    __shared__ float logS[64][HEADS];      // 1 KB
    __shared__ float logD[64][HEADS];      // 1 KB

    if (blockIdx.x >= GEMM_BLOCKS) {
        const int e = (blockIdx.x - GEMM_BLOCKS) * 256 + threadIdx.x;
        if (e < N_EDGES)
            epos[e] = atomicAdd(&cnt[ei[N_EDGES + e] << CNT_SHIFT], 1);
        return;
    }

    const int tid = threadIdx.x;
    const int n0  = blockIdx.x * 64;

    // zero the logit accumulators (256 threads == 64*4 entries)
    logS[tid >> 2][tid & 3] = 0.f;
    logD[tid >> 2][tid & 3] = 0.f;

    #pragma unroll
    for (int i = 0; i < 8; ++i) {
        const int e    = i * 256 + tid;
        const int g    = e >> 9;
        const int kk   = (e >> 6) & 7;
        const int lane = e & 63;
        const int cL   = lane & 15, qd = lane >> 4;
        const int row  = n0 + g * 16 + cL;
        const int k0   = kk * 32 + qd * 8;
        uint4 u = make_uint4(0u, 0u, 0u, 0u);
        if (row < N_NODES) {
            const float4 a = *reinterpret_cast<const float4*>(x + (size_t)row * IN_CH + k0);
            const float4 b = *reinterpret_cast<const float4*>(x + (size_t)row * IN_CH + k0 + 4);
            u.x = pack2(a.x, a.y); u.y = pack2(a.z, a.w);
            u.z = pack2(b.x, b.y); u.w = pack2(b.z, b.w);
        }
        Alds[(g * NKK + kk) * 64 + lane] = u;
    }
    __syncthreads();

    const int lane = tid & 63;
    const int wv   = tid >> 6;
    const int colL = lane & 15, quad = lane >> 4;

    f32x4 acc[4][5];
    #pragma unroll
    for (int rg = 0; rg < 4; ++rg)
        #pragma unroll
        for (int j = 0; j < 5; ++j) acc[rg][j] = (f32x4){0.f, 0.f, 0.f, 0.f};

    for (int kk = 0; kk < NKK; ++kk) {
        uint4 bu[5];
        #pragma unroll
        for (int j = 0; j < 5; ++j)
            bu[j] = Bp[(kk * NTILES + j * 4 + wv) * 64 + lane];
        #pragma unroll
        for (int rg = 0; rg < 4; ++rg) {
            const short8 a = as_short8(Alds[(rg * NKK + kk) * 64 + lane]);
            #pragma unroll
            for (int j = 0; j < 5; ++j)
                acc[rg][j] = __builtin_amdgcn_mfma_f32_16x16x32_bf16(
                    a, as_short8(bu[j]), acc[rg][j], 0, 0, 0);
        }
    }

    // ---- store xw2 / xres (unchanged) ----
    #pragma unroll
    for (int rg = 0; rg < 4; ++rg) {
        #pragma unroll
        for (int r = 0; r < 4; ++r) {
            const int row = n0 + rg * 16 + quad * 4 + r;
            if (row < N_NODES) {
                xw2[(size_t)row * 64 + wv * 16 + colL] = make_uint2(
                    pack2(acc[rg][0][r], acc[rg][1][r]),
                    pack2(acc[rg][2][r], acc[rg][3][r]));
                xres[(size_t)row * OUT_CH + wv * 16 + colL] = acc[rg][4][r];
            }
        }
    }

    // ---- fused logits ----
    float aSr[HEADS], aDr[HEADS];
    #pragma unroll
    for (int h = 0; h < HEADS; ++h) {
        aSr[h] = attS[h * 64 + wv * 16 + colL];
        aDr[h] = attD[h * 64 + wv * 16 + colL];
    }
    #pragma unroll
    for (int rg = 0; rg < 4; ++rg) {
        #pragma unroll
        for (int h = 0; h < HEADS; ++h) {
            #pragma unroll
            for (int r = 0; r < 4; ++r) {
                float vS = acc[rg][h][r] * aSr[h];
                float vD = acc[rg][h][r] * aDr[h];
                #pragma unroll
                for (int m = 1; m < 16; m <<= 1) {      // stays within quad
                    vS += __shfl_xor(vS, m);
                    vD += __shfl_xor(vD, m);
                }
                if (colL == 0) {
                    atomicAdd(&logS[rg * 16 + quad * 4 + r][h], vS);
                    atomicAdd(&logD[rg * 16 + quad * 4 + r][h], vD);
                }
            }
        }
    }
    __syncthreads();
    {
        const int rl = tid >> 2, h = tid & 3;
        const int row = n0 + rl;
        if (row < N_NODES) {
            asrc[(size_t)row * HEADS + h] = logS[rl][h];
            adst[(size_t)row * HEADS + h] = logD[rl][h];
        }
    }
}

// ---------------------------------------------------------------------------
// scan_local: per-256-chunk exclusive scan of (padded) cnt; block sums to
// bsum. Consumers inline the 196-element bsum scan (L2-hot).
// ---------------------------------------------------------------------------
__global__ __launch_bounds__(256) void scan_local(
    const int* __restrict__ cnt, int* __restrict__ lscan, int* __restrict__ bsum)
{
    __shared__ int ws[4];
    const int t = threadIdx.x, lane = t & 63, w = t >> 6;
    const int i = blockIdx.x * 256 + t;
    const int v = (i < N_NODES) ? cnt[i << CNT_SHIFT] : 0;
    int sc = v;
    #pragma unroll
    for (int off = 1; off < 64; off <<= 1) {
        const int n = __shfl_up(sc, off);
        if (lane >= off) sc += n;
    }
    if (lane == 63) ws[w] = sc;
    __syncthreads();
    int prefix = 0;
    for (int j = 0; j < w; ++j) prefix += ws[j];
    if (i < N_NODES) lscan[i] = prefix + sc - v;
    if (t == 255) bsum[blockIdx.x] = prefix + sc;
}

// ---------------------------------------------------------------------------
// scatter_edges: ATOMIC-FREE scatter — slot comes from epos[e] captured
// during the histogram. Coalesced reads + one random 4 B write per edge.
// ---------------------------------------------------------------------------
__global__ __launch_bounds__(256) void scatter_edges(
    const int* __restrict__ ei, const int* __restrict__ epos,
    const int* __restrict__ lscan, const int* __restrict__ bsum,
    int* __restrict__ esrc)
{
    __shared__ int bsx[256];
    __shared__ int ws[4];
    const int t = threadIdx.x;
    const int lane = t & 63, wv = t >> 6;

    const int v = (t < SCAN_BLOCKS) ? bsum[t] : 0;
    int sc = v;
    #pragma unroll
    for (int off = 1; off < 64; off <<= 1) {
        const int n = __shfl_up(sc, off);
        if (lane >= off) sc += n;
    }
    if (lane == 63) ws[wv] = sc;
    __syncthreads();
    int prefix = 0;
    for (int j = 0; j < wv; ++j) prefix += ws[j];
    bsx[t] = prefix + sc - v;
    __syncthreads();

    const int e = blockIdx.x * 256 + t;
    if (e < N_EDGES) {
        const int d = ei[N_EDGES + e];
        esrc[lscan[d] + bsx[d >> 8] + epos[e]] = ei[e];
    }
}

// ---------------------------------------------------------------------------
// aggregate, single-pass, unnormalized head accumulators. Inline bsum scan.
// Per 64-edge chunk: lane-parallel gather asrc + exp -> LDS stash; per edge:
// uniform-addr LDS broadcast + ONE dwordx2 gather + 4 fma. 4x unroll, live
// regs kept low (latency-bound: occupancy > ILP — R6 lesson).
// R1 established aggregate is at its structural floor: 214 MB = 8 XCD x
// 25.6 MB compulsory L2 streaming at ~3.3 TB/s (MSHR-bound; extra wave-level
// MLP was a measured no-op). Split into two dispatches for rocprof top-5
// visibility (diagnostic; ~3-5us cost, remove once scatter cost is known).
// ---------------------------------------------------------------------------
__global__ __launch_bounds__(256) void aggregate(
    const int* __restrict__ esrc, const int* __restrict__ lscan,
    const int* __restrict__ bsum, const int* __restrict__ cnt,
    const float* __restrict__ asrc, const float* __restrict__ adst,
    const uint2* __restrict__ xw2, const float* __restrict__ xres,
    const float* __restrict__ bias, float* __restrict__ out,
    const int d0)
{
    __shared__ float4 wbuf[4][64];
    __shared__ int    sbuf[4][64];
    __shared__ int    bsx[256];
    __shared__ int    ws[4];
    const int t = threadIdx.x;
    const int lane = t & 63;
    const int wv   = t >> 6;

    {
        const int v = (t < SCAN_BLOCKS) ? bsum[t] : 0;
        int sc = v;
        #pragma unroll
        for (int off = 1; off < 64; off <<= 1) {
            const int n = __shfl_up(sc, off);
            if (lane >= off) sc += n;
        }
        if (lane == 63) ws[wv] = sc;
        __syncthreads();
        int prefix = 0;
        for (int j = 0; j < wv; ++j) prefix += ws[j];
        bsx[t] = prefix + sc - v;
        __syncthreads();
    }

    const int d = d0 + blockIdx.x * 4 + wv;
    const int row = lscan[d] + bsx[d >> 8];
    const int deg = cnt[d << CNT_SHIFT];
    const float4 ad = *reinterpret_cast<const float4*>(adst + (size_t)d * 4);
    const char* xwB = (const char*)xw2;
    const int laneB = lane << 3;

    float dn0 = 0.f, dn1 = 0.f, dn2 = 0.f, dn3 = 0.f;
    float ac0 = 0.f, ac1 = 0.f, ac2 = 0.f, ac3 = 0.f;

    for (int base = 0; base < deg; base += 64) {
        const int m = min(64, deg - base);
        if (lane < m) {
            const int s = esrc[row + base + lane];
            const float4 as = *reinterpret_cast<const float4*>(asrc + (size_t)s * 4);
            const float e0 = __expf(lrelu(as.x + ad.x));
            const float e1 = __expf(lrelu(as.y + ad.y));
            const float e2 = __expf(lrelu(as.z + ad.z));
            const float e3 = __expf(lrelu(as.w + ad.w));
            dn0 += e0; dn1 += e1; dn2 += e2; dn3 += e3;
            wbuf[wv][lane] = make_float4(e0, e1, e2, e3);
            sbuf[wv][lane] = s << 9;   // *512 B node row
        }
        int j = 0;
        for (; j + 4 <= m; j += 4) {
            uint2 v0 = *(const uint2*)(xwB + sbuf[wv][j]     + laneB);
            uint2 v1 = *(const uint2*)(xwB + sbuf[wv][j + 1] + laneB);
            uint2 v2 = *(const uint2*)(xwB + sbuf[wv][j + 2] + laneB);
            uint2 v3 = *(const uint2*)(xwB + sbuf[wv][j + 3] + laneB);
            {
                const float4 w = wbuf[wv][j];
                ac0 = fmaf(w.x, bflo(v0.x), ac0); ac1 = fmaf(w.y, bfhi(v0.x), ac1);
                ac2 = fmaf(w.z, bflo(v0.y), ac2); ac3 = fmaf(w.w, bfhi(v0.y), ac3);
            }
            {
                const float4 w = wbuf[wv][j + 1];
                ac0 = fmaf(w.x, bflo(v1.x), ac0); ac1 = fmaf(w.y, bfhi(v1.x), ac1);
                ac2 = fmaf(w.z, bflo(v1.y), ac2); ac3 = fmaf(w.w, bfhi(v1.y), ac3);
            }
            {
                const float4 w = wbuf[wv][j + 2];
                ac0 = fmaf(w.x, bflo(v2.x), ac0); ac1 = fmaf(w.y, bfhi(v2.x), ac1);
                ac2 = fmaf(w.z, bflo(v2.y), ac2); ac3 = fmaf(w.w, bfhi(v2.y), ac3);
            }
            {
                const float4 w = wbuf[wv][j + 3];
                ac0 = fmaf(w.x, bflo(v3.x), ac0); ac1 = fmaf(w.y, bfhi(v3.x), ac1);
                ac2 = fmaf(w.z, bflo(v3.y), ac2); ac3 = fmaf(w.w, bfhi(v3.y), ac3);
            }
        }
        for (; j < m; ++j) {
            const float4 w = wbuf[wv][j];
            const uint2 v = *(const uint2*)(xwB + sbuf[wv][j] + laneB);
            ac0 = fmaf(w.x, bflo(v.x), ac0);
            ac1 = fmaf(w.y, bfhi(v.x), ac1);
            ac2 = fmaf(w.z, bflo(v.y), ac2);
            ac3 = fmaf(w.w, bfhi(v.y), ac3);
        }
    }

    #pragma unroll
    for (int off = 32; off >= 1; off >>= 1) {
        dn0 += __shfl_xor(dn0, off);
        dn1 += __shfl_xor(dn1, off);
        dn2 += __shfl_xor(dn2, off);
        dn3 += __shfl_xor(dn3, off);
    }
    // self-loop
    const float4 asd = *reinterpret_cast<const float4*>(asrc + (size_t)d * 4);
    const float s0 = __expf(lrelu(asd.x + ad.x));
    const float s1 = __expf(lrelu(asd.y + ad.y));
    const float s2 = __expf(lrelu(asd.z + ad.z));
    const float s3 = __expf(lrelu(asd.w + ad.w));
    const uint2 u = xw2[(size_t)d * 64 + lane];
    ac0 = fmaf(s0, bflo(u.x), ac0); ac1 = fmaf(s1, bfhi(u.x), ac1);
    ac2 = fmaf(s2, bflo(u.y), ac2); ac3 = fmaf(s3, bfhi(u.y), ac3);
    const float i0 = 0.25f / (dn0 + s0);
    const float i1 = 0.25f / (dn1 + s1);
    const float i2 = 0.25f / (dn2 + s2);
    const float i3 = 0.25f / (dn3 + s3);
    const float v = ac0 * i0 + ac1 * i1 + ac2 * i2 + ac3 * i3
                  + bias[lane] + xres[(size_t)d * OUT_CH + lane];
    out[(size_t)d * OUT_CH + lane] = fmaxf(v, 0.f);
}

extern "C" void kernel_launch(void* const* d_in, const int* in_sizes, int n_in,
                              void* d_out, int out_size, void* d_ws, size_t ws_size,
                              hipStream_t stream) {
    const float* x    = (const float*)d_in[0];
    const int*   ei   = (const int*)d_in[1];
    const float* W    = (const float*)d_in[2];
    const float* attS = (const float*)d_in[3];
    const float* attD = (const float*)d_in[4];
    const float* bias = (const float*)d_in[5];
    const float* Wres = (const float*)d_in[6];
    float* out = (float*)d_out;

    char* p = (char*)d_ws;
    uint4*    Bp    = (uint4*)p;    p += (size_t)NKK * NTILES * 64 * 16;  // 160 KB
    uint2*    xw2   = (uint2*)p;    p += (size_t)N_NODES * 64 * 8;        // 25.6 MB
    float*    xres  = (float*)p;    p += (size_t)N_NODES * OUT_CH * 4;    // 12.8 MB
    float*    asrc  = (float*)p;    p += (size_t)N_NODES * HEADS * 4;
    float*    adst  = (float*)p;    p += (size_t)N_NODES * HEADS * 4;
    int*      cnt   = (int*)p;      p += (size_t)N_NODES * 4 * (1 << CNT_SHIFT); // 3.2 MB padded
    int*      lscan = (int*)p;      p += (size_t)N_NODES * 4;
    int*      bsum  = (int*)p;      p += 256 * 4;
    int*      epos  = (int*)p;      p += (size_t)N_EDGES * 4;
    int*      esrc  = (int*)p;      p += (size_t)N_EDGES * 4;

    hipMemsetAsync(cnt, 0, (size_t)N_NODES * sizeof(int) * (1 << CNT_SHIFT), stream);

    pack_B<<<PACK_BLOCKS, 256, 0, stream>>>(W, Wres, Bp);
    hist_gemm<<<GEMM_BLOCKS + HIST_BLOCKS, 256, 0, stream>>>(
        x, Bp, xw2, xres, ei, cnt, epos, attS, attD, asrc, adst);
    scan_local<<<SCAN_BLOCKS, 256, 0, stream>>>(cnt, lscan, bsum);
    scatter_edges<<<SCAT_BLOCKS, 256, 0, stream>>>(
        ei, epos, lscan, bsum, esrc);
    aggregate<<<AGG_BLOCKS, 256, 0, stream>>>(
        esrc, lscan, bsum, cnt, asrc, adst, xw2, xres, bias, out, 0);
    aggregate<<<AGG_BLOCKS, 256, 0, stream>>>(
        esrc, lscan, bsum, cnt, asrc, adst, xw2, xres, bias, out, 25000);
}

// Round 4
// 242.822 us; speedup vs baseline: 1.0430x; 1.0231x over previous
//
#include <hip/hip_runtime.h>
#include <math.h>

#define N_NODES 50000
#define N_EDGES 800000
#define IN_CH   256
#define OUT_CH  64
#define HEADS   4
#define NEG_SLOPE 0.2f
#define NCOLS   320           // W (256) || W_res (64)
#define NTILES  20            // NCOLS / 16
#define NKK     8             // IN_CH / 32
#define NXCD    8
#define PACK_BLOCKS 40        // NKK*NTILES*64 / 256
#define GEMM_BLOCKS 782       // (N_NODES+63)/64
#define SCAN_BLOCKS 196       // (N_NODES+255)/256
#define HIST_BLOCKS 3125      // N_EDGES/256
#define SCAT_BLOCKS 3125      // N_EDGES/256
#define AGG_BLOCKS  12500     // N_NODES/4 (single dispatch again — R2/R3 split
                              // cost ~2x xw2 streaming; diagnostic done)

typedef __attribute__((ext_vector_type(8))) short short8;
typedef __attribute__((ext_vector_type(4))) float f32x4;

__device__ __forceinline__ float lrelu(float v) {
    return v > 0.f ? v : NEG_SLOPE * v;
}
__device__ __forceinline__ unsigned bf16_rne(float f) {
    unsigned u = __float_as_uint(f);
    return (u + 0x7FFFu + ((u >> 16) & 1u)) >> 16;
}
__device__ __forceinline__ unsigned pack2(float lo, float hi) {
    return bf16_rne(lo) | (bf16_rne(hi) << 16);
}
__device__ __forceinline__ float bflo(unsigned u) { return __uint_as_float(u << 16); }
__device__ __forceinline__ float bfhi(unsigned u) { return __uint_as_float(u & 0xFFFF0000u); }
__device__ __forceinline__ short8 as_short8(uint4 u) {
    union { uint4 u4; short8 s8; } cv; cv.u4 = u; return cv.s8;
}

// ---------------------------------------------------------------------------
// pack_B: [W | W_res] fp32 -> bf16 MFMA B-fragment order (tiny, 40 blocks).
// ---------------------------------------------------------------------------
__global__ __launch_bounds__(256) void pack_B(
    const float* __restrict__ W, const float* __restrict__ Wres,
    uint4* __restrict__ Bp)
{
    const int idx  = blockIdx.x * 256 + threadIdx.x;   // 0..10239
    const int kk   = idx / (NTILES * 64);
    const int rem  = idx - kk * (NTILES * 64);
    const int t    = rem >> 6;
    const int lane = rem & 63;
    const int colL = lane & 15, quad = lane >> 4;
    const int col  = t * 16 + colL;
    const int k0   = kk * 32 + quad * 8;
    float v[8];
    #pragma unroll
    for (int j = 0; j < 8; ++j) {
        const int k = k0 + j;
        v[j] = (col < IN_CH) ? W[(size_t)k * IN_CH + col]
                             : Wres[(size_t)k * OUT_CH + (col - IN_CH)];
    }
    uint4 u;
    u.x = pack2(v[0], v[1]); u.y = pack2(v[2], v[3]);
    u.z = pack2(v[4], v[5]); u.w = pack2(v[6], v[7]);
    Bp[(kk * NTILES + t) * 64 + lane] = u;
}

// ---------------------------------------------------------------------------
// hist_gemm: fused independent halves.
//   blocks [0, GEMM_BLOCKS)          : MFMA node transform + FUSED LOGITS
//   blocks [GEMM_BLOCKS,+HIST_BLOCKS): PER-XCD histogram (R4).
// R4: device-scope atomics were the 75us pole (rate ~11 G/s, padding null ->
// op-rate not line-contention). Replace with 8 per-XCD count arrays: read the
// physical XCD via s_getreg(HW_REG_XCC_ID) [HW-verified, learn_hip m09] and
// atomicAdd at WORKGROUP scope -> RMW executes in the local XCD's L2 (all CUs
// of an XCD share that L2 -> atomic XCD-wide; partitions never mix XCDs).
// epos[e] = (xcd<<24) | pos-within-(xcd,dst). scan_local folds the 8 planes.
// ---------------------------------------------------------------------------
__global__ __launch_bounds__(256) void hist_gemm(
    const float* __restrict__ x, const uint4* __restrict__ Bp,
    uint2* __restrict__ xw2, float* __restrict__ xres,
    const int* __restrict__ ei, int* __restrict__ cnt8,
    int* __restrict__ epos,
    const float* __restrict__ attS, const float* __restrict__ attD,
    float* __restrict__ asrc, float* __restrict__ adst)
{
    __shared__ uint4 Alds[4 * NKK * 64];   // 32 KB
    __shared__ float logS[64][HEADS];      // 1 KB
    __shared__ float logD[64][HEADS];      // 1 KB

    if (blockIdx.x >= GEMM_BLOCKS) {
        const int e = (blockIdx.x - GEMM_BLOCKS) * 256 + threadIdx.x;
        if (e < N_EDGES) {
            int xcc;
            asm volatile("s_getreg_b32 %0, hwreg(HW_REG_XCC_ID)" : "=s"(xcc));
            xcc &= 7;
            const int d = ei[N_EDGES + e];
            const int pos = __hip_atomic_fetch_add(
                &cnt8[(size_t)xcc * N_NODES + d], 1,
                __ATOMIC_RELAXED, __HIP_MEMORY_SCOPE_WORKGROUP);
            epos[e] = (xcc << 24) | pos;
        }
        return;
    }

    const int tid = threadIdx.x;
    const int n0  = blockIdx.x * 64;

    // zero the logit accumulators (256 threads == 64*4 entries)
    logS[tid >> 2][tid & 3] = 0.f;
    logD[tid >> 2][tid & 3] = 0.f;

    #pragma unroll
    for (int i = 0; i < 8; ++i) {
        const int e    = i * 256 + tid;
        const int g    = e >> 9;
        const int kk   = (e >> 6) & 7;
        const int lane = e & 63;
        const int cL   = lane & 15, qd = lane >> 4;
        const int row  = n0 + g * 16 + cL;
        const int k0   = kk * 32 + qd * 8;
        uint4 u = make_uint4(0u, 0u, 0u, 0u);
        if (row < N_NODES) {
            const float4 a = *reinterpret_cast<const float4*>(x + (size_t)row * IN_CH + k0);
            const float4 b = *reinterpret_cast<const float4*>(x + (size_t)row * IN_CH + k0 + 4);
            u.x = pack2(a.x, a.y); u.y = pack2(a.z, a.w);
            u.z = pack2(b.x, b.y); u.w = pack2(b.z, b.w);
        }
        Alds[(g * NKK + kk) * 64 + lane] = u;
    }
    __syncthreads();

    const int lane = tid & 63;
    const int wv   = tid >> 6;
    const int colL = lane & 15, quad = lane >> 4;

    f32x4 acc[4][5];
    #pragma unroll
    for (int rg = 0; rg < 4; ++rg)
        #pragma unroll
        for (int j = 0; j < 5; ++j) acc[rg][j] = (f32x4){0.f, 0.f, 0.f, 0.f};

    for (int kk = 0; kk < NKK; ++kk) {
        uint4 bu[5];
        #pragma unroll
        for (int j = 0; j < 5; ++j)
            bu[j] = Bp[(kk * NTILES + j * 4 + wv) * 64 + lane];
        #pragma unroll
        for (int rg = 0; rg < 4; ++rg) {
            const short8 a = as_short8(Alds[(rg * NKK + kk) * 64 + lane]);
            #pragma unroll
            for (int j = 0; j < 5; ++j)
                acc[rg][j] = __builtin_amdgcn_mfma_f32_16x16x32_bf16(
                    a, as_short8(bu[j]), acc[rg][j], 0, 0, 0);
        }
    }

    // ---- store xw2 / xres ----
    #pragma unroll
    for (int rg = 0; rg < 4; ++rg) {
        #pragma unroll
        for (int r = 0; r < 4; ++r) {
            const int row = n0 + rg * 16 + quad * 4 + r;
            if (row < N_NODES) {
                xw2[(size_t)row * 64 + wv * 16 + colL] = make_uint2(
                    pack2(acc[rg][0][r], acc[rg][1][r]),
                    pack2(acc[rg][2][r], acc[rg][3][r]));
                xres[(size_t)row * OUT_CH + wv * 16 + colL] = acc[rg][4][r];
            }
        }
    }

    // ---- fused logits ----
    float aSr[HEADS], aDr[HEADS];
    #pragma unroll
    for (int h = 0; h < HEADS; ++h) {
        aSr[h] = attS[h * 64 + wv * 16 + colL];
        aDr[h] = attD[h * 64 + wv * 16 + colL];
    }
    #pragma unroll
    for (int rg = 0; rg < 4; ++rg) {
        #pragma unroll
        for (int h = 0; h < HEADS; ++h) {
            #pragma unroll
            for (int r = 0; r < 4; ++r) {
                float vS = acc[rg][h][r] * aSr[h];
                float vD = acc[rg][h][r] * aDr[h];
                #pragma unroll
                for (int m = 1; m < 16; m <<= 1) {      // stays within quad
                    vS += __shfl_xor(vS, m);
                    vD += __shfl_xor(vD, m);
                }
                if (colL == 0) {
                    atomicAdd(&logS[rg * 16 + quad * 4 + r][h], vS);
                    atomicAdd(&logD[rg * 16 + quad * 4 + r][h], vD);
                }
            }
        }
    }
    __syncthreads();
    {
        const int rl = tid >> 2, h = tid & 3;
        const int row = n0 + rl;
        if (row < N_NODES) {
            asrc[(size_t)row * HEADS + h] = logS[rl][h];
            adst[(size_t)row * HEADS + h] = logD[rl][h];
        }
    }
}

// ---------------------------------------------------------------------------
// scan_local: fold the 8 per-XCD count planes (exclusive bases -> xbase,
// totals -> ctot), then per-256-chunk exclusive scan of totals; block sums
// to bsum. Consumers inline the 196-element bsum scan (L2-hot).
// ---------------------------------------------------------------------------
__global__ __launch_bounds__(256) void scan_local(
    const int* __restrict__ cnt8, int* __restrict__ ctot,
    int* __restrict__ xbase, int* __restrict__ lscan, int* __restrict__ bsum)
{
    __shared__ int ws[4];
    const int t = threadIdx.x, lane = t & 63, w = t >> 6;
    const int i = blockIdx.x * 256 + t;
    int v = 0;
    if (i < N_NODES) {
        int run = 0;
        #pragma unroll
        for (int xc = 0; xc < NXCD; ++xc) {
            xbase[(size_t)xc * N_NODES + i] = run;
            run += cnt8[(size_t)xc * N_NODES + i];
        }
        v = run;
        ctot[i] = v;
    }
    int sc = v;
    #pragma unroll
    for (int off = 1; off < 64; off <<= 1) {
        const int n = __shfl_up(sc, off);
        if (lane >= off) sc += n;
    }
    if (lane == 63) ws[w] = sc;
    __syncthreads();
    int prefix = 0;
    for (int j = 0; j < w; ++j) prefix += ws[j];
    if (i < N_NODES) lscan[i] = prefix + sc - v;
    if (t == 255) bsum[blockIdx.x] = prefix + sc;
}

// ---------------------------------------------------------------------------
// scatter_edges: ATOMIC-FREE scatter — slot = global dst base + per-XCD base
// + position captured during the histogram. Coalesced reads, two random 4 B
// gathers (lscan[d], xbase[x][d], both L2/L3-hot), one random 4 B write.
// ---------------------------------------------------------------------------
__global__ __launch_bounds__(256) void scatter_edges(
    const int* __restrict__ ei, const int* __restrict__ epos,
    const int* __restrict__ lscan, const int* __restrict__ bsum,
    const int* __restrict__ xbase, int* __restrict__ esrc)
{
    __shared__ int bsx[256];
    __shared__ int ws[4];
    const int t = threadIdx.x;
    const int lane = t & 63, wv = t >> 6;

    const int v = (t < SCAN_BLOCKS) ? bsum[t] : 0;
    int sc = v;
    #pragma unroll
    for (int off = 1; off < 64; off <<= 1) {
        const int n = __shfl_up(sc, off);
        if (lane >= off) sc += n;
    }
    if (lane == 63) ws[wv] = sc;
    __syncthreads();
    int prefix = 0;
    for (int j = 0; j < wv; ++j) prefix += ws[j];
    bsx[t] = prefix + sc - v;
    __syncthreads();

    const int e = blockIdx.x * 256 + t;
    if (e < N_EDGES) {
        const int d = ei[N_EDGES + e];
        const int p = epos[e];
        const int xc = p >> 24;
        esrc[lscan[d] + bsx[d >> 8] + xbase[(size_t)xc * N_NODES + d]
             + (p & 0xFFFFFF)] = ei[e];
    }
}

// ---------------------------------------------------------------------------
// aggregate, single-pass, unnormalized head accumulators. Inline bsum scan.
// Per 64-edge chunk: lane-parallel gather asrc + exp -> LDS stash; per edge:
// uniform-addr LDS broadcast + ONE dwordx2 gather + 4 fma. 4x unroll, live
// regs kept low (latency-bound: occupancy > ILP).
// R1 established this is at its structural floor: 214 MB = 8 XCD x 25.6 MB
// compulsory L2 streaming of xw2 at ~3.3 TB/s (request-rate/MSHR-bound;
// extra wave-level MLP was a measured no-op). Single dispatch (R2/R3 split
// nearly doubled the compulsory streaming).
// ---------------------------------------------------------------------------
__global__ __launch_bounds__(256) void aggregate(
    const int* __restrict__ esrc, const int* __restrict__ lscan,
    const int* __restrict__ bsum, const int* __restrict__ ctot,
    const float* __restrict__ asrc, const float* __restrict__ adst,
    const uint2* __restrict__ xw2, const float* __restrict__ xres,
    const float* __restrict__ bias, float* __restrict__ out)
{
    __shared__ float4 wbuf[4][64];
    __shared__ int    sbuf[4][64];
    __shared__ int    bsx[256];
    __shared__ int    ws[4];
    const int t = threadIdx.x;
    const int lane = t & 63;
    const int wv   = t >> 6;

    {
        const int v = (t < SCAN_BLOCKS) ? bsum[t] : 0;
        int sc = v;
        #pragma unroll
        for (int off = 1; off < 64; off <<= 1) {
            const int n = __shfl_up(sc, off);
            if (lane >= off) sc += n;
        }
        if (lane == 63) ws[wv] = sc;
        __syncthreads();
        int prefix = 0;
        for (int j = 0; j < wv; ++j) prefix += ws[j];
        bsx[t] = prefix + sc - v;
        __syncthreads();
    }

    const int d = blockIdx.x * 4 + wv;                   // 12500*4 = 50000
    const int row = lscan[d] + bsx[d >> 8];
    const int deg = ctot[d];
    const float4 ad = *reinterpret_cast<const float4*>(adst + (size_t)d * 4);
    const char* xwB = (const char*)xw2;
    const int laneB = lane << 3;

    float dn0 = 0.f, dn1 = 0.f, dn2 = 0.f, dn3 = 0.f;
    float ac0 = 0.f, ac1 = 0.f, ac2 = 0.f, ac3 = 0.f;

    for (int base = 0; base < deg; base += 64) {
        const int m = min(64, deg - base);
        if (lane < m) {
            const int s = esrc[row + base + lane];
            const float4 as = *reinterpret_cast<const float4*>(asrc + (size_t)s * 4);
            const float e0 = __expf(lrelu(as.x + ad.x));
            const float e1 = __expf(lrelu(as.y + ad.y));
            const float e2 = __expf(lrelu(as.z + ad.z));
            const float e3 = __expf(lrelu(as.w + ad.w));
            dn0 += e0; dn1 += e1; dn2 += e2; dn3 += e3;
            wbuf[wv][lane] = make_float4(e0, e1, e2, e3);
            sbuf[wv][lane] = s << 9;   // *512 B node row
        }
        int j = 0;
        for (; j + 4 <= m; j += 4) {
            uint2 v0 = *(const uint2*)(xwB + sbuf[wv][j]     + laneB);
            uint2 v1 = *(const uint2*)(xwB + sbuf[wv][j + 1] + laneB);
            uint2 v2 = *(const uint2*)(xwB + sbuf[wv][j + 2] + laneB);
            uint2 v3 = *(const uint2*)(xwB + sbuf[wv][j + 3] + laneB);
            {
                const float4 w = wbuf[wv][j];
                ac0 = fmaf(w.x, bflo(v0.x), ac0); ac1 = fmaf(w.y, bfhi(v0.x), ac1);
                ac2 = fmaf(w.z, bflo(v0.y), ac2); ac3 = fmaf(w.w, bfhi(v0.y), ac3);
            }
            {
                const float4 w = wbuf[wv][j + 1];
                ac0 = fmaf(w.x, bflo(v1.x), ac0); ac1 = fmaf(w.y, bfhi(v1.x), ac1);
                ac2 = fmaf(w.z, bflo(v1.y), ac2); ac3 = fmaf(w.w, bfhi(v1.y), ac3);
            }
            {
                const float4 w = wbuf[wv][j + 2];
                ac0 = fmaf(w.x, bflo(v2.x), ac0); ac1 = fmaf(w.y, bfhi(v2.x), ac1);
                ac2 = fmaf(w.z, bflo(v2.y), ac2); ac3 = fmaf(w.w, bfhi(v2.y), ac3);
            }
            {
                const float4 w = wbuf[wv][j + 3];
                ac0 = fmaf(w.x, bflo(v3.x), ac0); ac1 = fmaf(w.y, bfhi(v3.x), ac1);
                ac2 = fmaf(w.z, bflo(v3.y), ac2); ac3 = fmaf(w.w, bfhi(v3.y), ac3);
            }
        }
        for (; j < m; ++j) {
            const float4 w = wbuf[wv][j];
            const uint2 v = *(const uint2*)(xwB + sbuf[wv][j] + laneB);
            ac0 = fmaf(w.x, bflo(v.x), ac0);
            ac1 = fmaf(w.y, bfhi(v.x), ac1);
            ac2 = fmaf(w.z, bflo(v.y), ac2);
            ac3 = fmaf(w.w, bfhi(v.y), ac3);
        }
    }

    #pragma unroll
    for (int off = 32; off >= 1; off >>= 1) {
        dn0 += __shfl_xor(dn0, off);
        dn1 += __shfl_xor(dn1, off);
        dn2 += __shfl_xor(dn2, off);
        dn3 += __shfl_xor(dn3, off);
    }
    // self-loop
    const float4 asd = *reinterpret_cast<const float4*>(asrc + (size_t)d * 4);
    const float s0 = __expf(lrelu(asd.x + ad.x));
    const float s1 = __expf(lrelu(asd.y + ad.y));
    const float s2 = __expf(lrelu(asd.z + ad.z));
    const float s3 = __expf(lrelu(asd.w + ad.w));
    const uint2 u = xw2[(size_t)d * 64 + lane];
    ac0 = fmaf(s0, bflo(u.x), ac0); ac1 = fmaf(s1, bfhi(u.x), ac1);
    ac2 = fmaf(s2, bflo(u.y), ac2); ac3 = fmaf(s3, bfhi(u.y), ac3);
    const float i0 = 0.25f / (dn0 + s0);
    const float i1 = 0.25f / (dn1 + s1);
    const float i2 = 0.25f / (dn2 + s2);
    const float i3 = 0.25f / (dn3 + s3);
    const float v = ac0 * i0 + ac1 * i1 + ac2 * i2 + ac3 * i3
                  + bias[lane] + xres[(size_t)d * OUT_CH + lane];
    out[(size_t)d * OUT_CH + lane] = fmaxf(v, 0.f);
}

extern "C" void kernel_launch(void* const* d_in, const int* in_sizes, int n_in,
                              void* d_out, int out_size, void* d_ws, size_t ws_size,
                              hipStream_t stream) {
    const float* x    = (const float*)d_in[0];
    const int*   ei   = (const int*)d_in[1];
    const float* W    = (const float*)d_in[2];
    const float* attS = (const float*)d_in[3];
    const float* attD = (const float*)d_in[4];
    const float* bias = (const float*)d_in[5];
    const float* Wres = (const float*)d_in[6];
    float* out = (float*)d_out;

    char* p = (char*)d_ws;
    uint4*    Bp    = (uint4*)p;    p += (size_t)NKK * NTILES * 64 * 16;  // 160 KB
    uint2*    xw2   = (uint2*)p;    p += (size_t)N_NODES * 64 * 8;        // 25.6 MB
    float*    xres  = (float*)p;    p += (size_t)N_NODES * OUT_CH * 4;    // 12.8 MB
    float*    asrc  = (float*)p;    p += (size_t)N_NODES * HEADS * 4;
    float*    adst  = (float*)p;    p += (size_t)N_NODES * HEADS * 4;
    int*      cnt8  = (int*)p;      p += (size_t)NXCD * N_NODES * 4;      // 1.6 MB
    int*      ctot  = (int*)p;      p += (size_t)N_NODES * 4;
    int*      xbase = (int*)p;      p += (size_t)NXCD * N_NODES * 4;      // 1.6 MB
    int*      lscan = (int*)p;      p += (size_t)N_NODES * 4;
    int*      bsum  = (int*)p;      p += 256 * 4;
    int*      epos  = (int*)p;      p += (size_t)N_EDGES * 4;
    int*      esrc  = (int*)p;      p += (size_t)N_EDGES * 4;

    hipMemsetAsync(cnt8, 0, (size_t)NXCD * N_NODES * sizeof(int), stream);

    pack_B<<<PACK_BLOCKS, 256, 0, stream>>>(W, Wres, Bp);
    hist_gemm<<<GEMM_BLOCKS + HIST_BLOCKS, 256, 0, stream>>>(
        x, Bp, xw2, xres, ei, cnt8, epos, attS, attD, asrc, adst);
    scan_local<<<SCAN_BLOCKS, 256, 0, stream>>>(cnt8, ctot, xbase, lscan, bsum);
    scatter_edges<<<SCAT_BLOCKS, 256, 0, stream>>>(
        ei, epos, lscan, bsum, xbase, esrc);
    aggregate<<<AGG_BLOCKS, 256, 0, stream>>>(
        esrc, lscan, bsum, ctot, asrc, adst, xw2, xres, bias, out);
}

// Round 5
// 241.010 us; speedup vs baseline: 1.0508x; 1.0075x over previous
//
#include <hip/hip_runtime.h>
#include <math.h>

#define N_NODES 50000
#define N_EDGES 800000
#define IN_CH   256
#define OUT_CH  64
#define HEADS   4
#define NEG_SLOPE 0.2f
#define NCOLS   320           // W (256) || W_res (64)
#define NTILES  20            // NCOLS / 16
#define NKK     8             // IN_CH / 32
#define PACK_BLOCKS 40        // NKK*NTILES*64 / 256
#define GEMM_BLOCKS 782       // (N_NODES+63)/64
#define SCAN_BLOCKS 196       // (N_NODES+255)/256
#define NBINS   391           // ceil(N_NODES/128): bin = dst>>7
#define P1_BLOCKS 256         // edge-partition blocks
#define EPB     3125          // edges per partition block = N_EDGES/256
#define AGG_BLOCKS 12500      // N_NODES/4

typedef __attribute__((ext_vector_type(8))) short short8;
typedef __attribute__((ext_vector_type(4))) float f32x4;

__device__ __forceinline__ float lrelu(float v) {
    return v > 0.f ? v : NEG_SLOPE * v;
}
__device__ __forceinline__ unsigned bf16_rne(float f) {
    unsigned u = __float_as_uint(f);
    return (u + 0x7FFFu + ((u >> 16) & 1u)) >> 16;
}
__device__ __forceinline__ unsigned pack2(float lo, float hi) {
    return bf16_rne(lo) | (bf16_rne(hi) << 16);
}
__device__ __forceinline__ float bflo(unsigned u) { return __uint_as_float(u << 16); }
__device__ __forceinline__ float bfhi(unsigned u) { return __uint_as_float(u & 0xFFFF0000u); }
__device__ __forceinline__ short8 as_short8(uint4 u) {
    union { uint4 u4; short8 s8; } cv; cv.u4 = u; return cv.s8;
}

// ---------------------------------------------------------------------------
// pack_B: [W | W_res] fp32 -> bf16 MFMA B-fragment order (tiny, 40 blocks).
// ---------------------------------------------------------------------------
__global__ __launch_bounds__(256) void pack_B(
    const float* __restrict__ W, const float* __restrict__ Wres,
    uint4* __restrict__ Bp)
{
    const int idx  = blockIdx.x * 256 + threadIdx.x;   // 0..10239
    const int kk   = idx / (NTILES * 64);
    const int rem  = idx - kk * (NTILES * 64);
    const int t    = rem >> 6;
    const int lane = rem & 63;
    const int colL = lane & 15, quad = lane >> 4;
    const int col  = t * 16 + colL;
    const int k0   = kk * 32 + quad * 8;
    float v[8];
    #pragma unroll
    for (int j = 0; j < 8; ++j) {
        const int k = k0 + j;
        v[j] = (col < IN_CH) ? W[(size_t)k * IN_CH + col]
                             : Wres[(size_t)k * OUT_CH + (col - IN_CH)];
    }
    uint4 u;
    u.x = pack2(v[0], v[1]); u.y = pack2(v[2], v[3]);
    u.z = pack2(v[4], v[5]); u.w = pack2(v[6], v[7]);
    Bp[(kk * NTILES + t) * 64 + lane] = u;
}

// ---------------------------------------------------------------------------
// gemm_hist: fused independent halves.
//   blocks [0, GEMM_BLOCKS)          : MFMA node transform + FUSED LOGITS
//   blocks [GEMM_BLOCKS,+P1_BLOCKS)  : R5 coarse partition histogram.
// R5: 800k returning GLOBAL atomics were a ~73us wall at ~11 G ops/s
// (invariant under padding [R3] and per-XCD scope [R4] -> L2 returning-
// atomic op rate). Replaced with an atomic-FREE two-level radix partition:
// each of 256 blocks LDS-histograms its contiguous 3125-edge chunk into
// NBINS=391 bins (bin = dst>>7) and writes a [bin][block] count matrix M.
// ---------------------------------------------------------------------------
__global__ __launch_bounds__(256) void gemm_hist(
    const float* __restrict__ x, const uint4* __restrict__ Bp,
    uint2* __restrict__ xw2, float* __restrict__ xres,
    const int* __restrict__ ei, int* __restrict__ M,
    const float* __restrict__ attS, const float* __restrict__ attD,
    float* __restrict__ asrc, float* __restrict__ adst)
{
    __shared__ uint4 Alds[4 * NKK * 64];   // 32 KB
    __shared__ float logS[64][HEADS];      // 1 KB
    __shared__ float logD[64][HEADS];      // 1 KB

    if (blockIdx.x >= GEMM_BLOCKS) {
        const int blk = blockIdx.x - GEMM_BLOCKS;      // 0..255
        int* lh = (int*)Alds;                          // reuse 32 KB LDS
        for (int b = threadIdx.x; b < NBINS; b += 256) lh[b] = 0;
        __syncthreads();
        const int e0 = blk * EPB;
        #pragma unroll
        for (int r = 0; r < 13; ++r) {
            const int idx = (r << 8) + threadIdx.x;
            if (idx < EPB)
                atomicAdd(&lh[ei[N_EDGES + e0 + idx] >> 7], 1);
        }
        __syncthreads();
        for (int b = threadIdx.x; b < NBINS; b += 256)
            M[(size_t)b * P1_BLOCKS + blk] = lh[b];
        return;
    }

    const int tid = threadIdx.x;
    const int n0  = blockIdx.x * 64;

    // zero the logit accumulators (256 threads == 64*4 entries)
    logS[tid >> 2][tid & 3] = 0.f;
    logD[tid >> 2][tid & 3] = 0.f;

    #pragma unroll
    for (int i = 0; i < 8; ++i) {
        const int e    = i * 256 + tid;
        const int g    = e >> 9;
        const int kk   = (e >> 6) & 7;
        const int lane = e & 63;
        const int cL   = lane & 15, qd = lane >> 4;
        const int row  = n0 + g * 16 + cL;
        const int k0   = kk * 32 + qd * 8;
        uint4 u = make_uint4(0u, 0u, 0u, 0u);
        if (row < N_NODES) {
            const float4 a = *reinterpret_cast<const float4*>(x + (size_t)row * IN_CH + k0);
            const float4 b = *reinterpret_cast<const float4*>(x + (size_t)row * IN_CH + k0 + 4);
            u.x = pack2(a.x, a.y); u.y = pack2(a.z, a.w);
            u.z = pack2(b.x, b.y); u.w = pack2(b.z, b.w);
        }
        Alds[(g * NKK + kk) * 64 + lane] = u;
    }
    __syncthreads();

    const int lane = tid & 63;
    const int wv   = tid >> 6;
    const int colL = lane & 15, quad = lane >> 4;

    f32x4 acc[4][5];
    #pragma unroll
    for (int rg = 0; rg < 4; ++rg)
        #pragma unroll
        for (int j = 0; j < 5; ++j) acc[rg][j] = (f32x4){0.f, 0.f, 0.f, 0.f};

    for (int kk = 0; kk < NKK; ++kk) {
        uint4 bu[5];
        #pragma unroll
        for (int j = 0; j < 5; ++j)
            bu[j] = Bp[(kk * NTILES + j * 4 + wv) * 64 + lane];
        #pragma unroll
        for (int rg = 0; rg < 4; ++rg) {
            const short8 a = as_short8(Alds[(rg * NKK + kk) * 64 + lane]);
            #pragma unroll
            for (int j = 0; j < 5; ++j)
                acc[rg][j] = __builtin_amdgcn_mfma_f32_16x16x32_bf16(
                    a, as_short8(bu[j]), acc[rg][j], 0, 0, 0);
        }
    }

    // ---- store xw2 / xres ----
    #pragma unroll
    for (int rg = 0; rg < 4; ++rg) {
        #pragma unroll
        for (int r = 0; r < 4; ++r) {
            const int row = n0 + rg * 16 + quad * 4 + r;
            if (row < N_NODES) {
                xw2[(size_t)row * 64 + wv * 16 + colL] = make_uint2(
                    pack2(acc[rg][0][r], acc[rg][1][r]),
                    pack2(acc[rg][2][r], acc[rg][3][r]));
                xres[(size_t)row * OUT_CH + wv * 16 + colL] = acc[rg][4][r];
            }
        }
    }

    // ---- fused logits ----
    float aSr[HEADS], aDr[HEADS];
    #pragma unroll
    for (int h = 0; h < HEADS; ++h) {
        aSr[h] = attS[h * 64 + wv * 16 + colL];
        aDr[h] = attD[h * 64 + wv * 16 + colL];
    }
    #pragma unroll
    for (int rg = 0; rg < 4; ++rg) {
        #pragma unroll
        for (int h = 0; h < HEADS; ++h) {
            #pragma unroll
            for (int r = 0; r < 4; ++r) {
                float vS = acc[rg][h][r] * aSr[h];
                float vD = acc[rg][h][r] * aDr[h];
                #pragma unroll
                for (int m = 1; m < 16; m <<= 1) {      // stays within quad
                    vS += __shfl_xor(vS, m);
                    vD += __shfl_xor(vD, m);
                }
                if (colL == 0) {
                    atomicAdd(&logS[rg * 16 + quad * 4 + r][h], vS);
                    atomicAdd(&logD[rg * 16 + quad * 4 + r][h], vD);
                }
            }
        }
    }
    __syncthreads();
    {
        const int rl = tid >> 2, h = tid & 3;
        const int row = n0 + rl;
        if (row < N_NODES) {
            asrc[(size_t)row * HEADS + h] = logS[rl][h];
            adst[(size_t)row * HEADS + h] = logD[rl][h];
        }
    }
}

// ---------------------------------------------------------------------------
// binscan_M: one block per bin; exclusive-scan M[b][0..255] in place,
// total -> binCnt[b].
// ---------------------------------------------------------------------------
__global__ __launch_bounds__(256) void binscan_M(
    int* __restrict__ M, int* __restrict__ binCnt)
{
    __shared__ int ws[4];
    const int t = threadIdx.x, lane = t & 63, w = t >> 6;
    const int b = blockIdx.x;
    const int v = M[(size_t)b * P1_BLOCKS + t];
    int sc = v;
    #pragma unroll
    for (int off = 1; off < 64; off <<= 1) {
        const int n = __shfl_up(sc, off);
        if (lane >= off) sc += n;
    }
    if (lane == 63) ws[w] = sc;
    __syncthreads();
    int prefix = 0;
    for (int j = 0; j < w; ++j) prefix += ws[j];
    M[(size_t)b * P1_BLOCKS + t] = prefix + sc - v;
    if (t == 255) binCnt[b] = prefix + sc;
}

// ---------------------------------------------------------------------------
// binstart_scan: single block, exclusive scan of binCnt[0..NBINS) -> binStart.
// ---------------------------------------------------------------------------
__global__ __launch_bounds__(512) void binstart_scan(
    const int* __restrict__ binCnt, int* __restrict__ binStart)
{
    __shared__ int ws[8];
    const int t = threadIdx.x, lane = t & 63, w = t >> 6;
    const int v = (t < NBINS) ? binCnt[t] : 0;
    int sc = v;
    #pragma unroll
    for (int off = 1; off < 64; off <<= 1) {
        const int n = __shfl_up(sc, off);
        if (lane >= off) sc += n;
    }
    if (lane == 63) ws[w] = sc;
    __syncthreads();
    int prefix = 0;
    for (int j = 0; j < w; ++j) prefix += ws[j];
    if (t < NBINS) binStart[t] = prefix + sc - v;
}

// ---------------------------------------------------------------------------
// part_mid: 256 blocks; re-read own edge chunk, LDS running positions per
// bin, write bin-major records mid = (dst&127)<<17 | src. No global atomics;
// slots deterministic via binStart[b] + M[b][blk] + local position.
// ---------------------------------------------------------------------------
__global__ __launch_bounds__(256) void part_mid(
    const int* __restrict__ ei, const int* __restrict__ M,
    const int* __restrict__ binStart, unsigned* __restrict__ mid)
{
    __shared__ int baseL[NBINS];
    __shared__ int lh[NBINS];
    const int blk = blockIdx.x;
    for (int b = threadIdx.x; b < NBINS; b += 256) {
        baseL[b] = binStart[b] + M[(size_t)b * P1_BLOCKS + blk];
        lh[b] = 0;
    }
    __syncthreads();
    const int e0 = blk * EPB;
    #pragma unroll
    for (int r = 0; r < 13; ++r) {
        const int idx = (r << 8) + threadIdx.x;
        if (idx < EPB) {
            const int e = e0 + idx;
            const int d = ei[N_EDGES + e];
            const int b = d >> 7;
            const int pos = atomicAdd(&lh[b], 1);
            mid[baseL[b] + pos] = ((unsigned)(d & 127) << 17) | (unsigned)ei[e];
        }
    }
}

// ---------------------------------------------------------------------------
// count_fine: one block per bin; LDS-count the bin's 128 dsts -> cnt
// (coalesced write; covers all 50000 dsts, so no memset anywhere).
// ---------------------------------------------------------------------------
__global__ __launch_bounds__(256) void count_fine(
    const unsigned* __restrict__ mid, const int* __restrict__ binStart,
    const int* __restrict__ binCnt, int* __restrict__ cnt)
{
    __shared__ int c128[128];
    const int t = threadIdx.x, b = blockIdx.x;
    if (t < 128) c128[t] = 0;
    __syncthreads();
    const int base = binStart[b], n = binCnt[b];
    for (int i = t; i < n; i += 256)
        atomicAdd(&c128[mid[base + i] >> 17], 1);
    __syncthreads();
    if (t < 128) {
        const int d = (b << 7) + t;
        if (d < N_NODES) cnt[d] = c128[t];
    }
}

// ---------------------------------------------------------------------------
// scan_local: per-256-chunk exclusive scan of cnt; block sums to bsum.
// ---------------------------------------------------------------------------
__global__ __launch_bounds__(256) void scan_local(
    const int* __restrict__ cnt, int* __restrict__ lscan, int* __restrict__ bsum)
{
    __shared__ int ws[4];
    const int t = threadIdx.x, lane = t & 63, w = t >> 6;
    const int i = blockIdx.x * 256 + t;
    const int v = (i < N_NODES) ? cnt[i] : 0;
    int sc = v;
    #pragma unroll
    for (int off = 1; off < 64; off <<= 1) {
        const int n = __shfl_up(sc, off);
        if (lane >= off) sc += n;
    }
    if (lane == 63) ws[w] = sc;
    __syncthreads();
    int prefix = 0;
    for (int j = 0; j < w; ++j) prefix += ws[j];
    if (i < N_NODES) lscan[i] = prefix + sc - v;
    if (t == 255) bsum[blockIdx.x] = prefix + sc;
}

// ---------------------------------------------------------------------------
// scatter_fine: one block per bin; inline bsum scan; LDS positions per dst;
// write final CSR esrc. No global atomics.
// ---------------------------------------------------------------------------
__global__ __launch_bounds__(256) void scatter_fine(
    const unsigned* __restrict__ mid, const int* __restrict__ binStart,
    const int* __restrict__ binCnt, const int* __restrict__ lscan,
    const int* __restrict__ bsum, int* __restrict__ esrc)
{
    __shared__ int bsx[256];
    __shared__ int ws[4];
    __shared__ int lh[128];
    const int t = threadIdx.x, lane = t & 63, wv = t >> 6;

    const int v = (t < SCAN_BLOCKS) ? bsum[t] : 0;
    int sc = v;
    #pragma unroll
    for (int off = 1; off < 64; off <<= 1) {
        const int n = __shfl_up(sc, off);
        if (lane >= off) sc += n;
    }
    if (lane == 63) ws[wv] = sc;
    if (t < 128) lh[t] = 0;
    __syncthreads();
    int prefix = 0;
    for (int j = 0; j < wv; ++j) prefix += ws[j];
    bsx[t] = prefix + sc - v;
    __syncthreads();

    const int b = blockIdx.x;
    const int base = binStart[b], n = binCnt[b];
    for (int i = t; i < n; i += 256) {
        const unsigned m = mid[base + i];
        const int dlo = (int)(m >> 17);
        const int src = (int)(m & 0x1FFFFu);
        const int d = (b << 7) + dlo;
        const int pos = atomicAdd(&lh[dlo], 1);
        esrc[lscan[d] + bsx[d >> 8] + pos] = src;
    }
}

// ---------------------------------------------------------------------------
// aggregate, single-pass, unnormalized head accumulators. Inline bsum scan.
// Per 64-edge chunk: lane-parallel gather asrc + exp -> LDS stash; per edge:
// uniform-addr LDS broadcast + ONE dwordx2 gather + 4 fma. 4x unroll, live
// regs kept low (latency-bound: occupancy > ILP).
// R1 established this is at its structural floor: 214 MB = 8 XCD x 25.6 MB
// compulsory L2 streaming of xw2 at ~3.3 TB/s (request-rate/MSHR-bound).
// ---------------------------------------------------------------------------
__global__ __launch_bounds__(256) void aggregate(
    const int* __restrict__ esrc, const int* __restrict__ lscan,
    const int* __restrict__ bsum, const int* __restrict__ cnt,
    const float* __restrict__ asrc, const float* __restrict__ adst,
    const uint2* __restrict__ xw2, const float* __restrict__ xres,
    const float* __restrict__ bias, float* __restrict__ out)
{
    __shared__ float4 wbuf[4][64];
    __shared__ int    sbuf[4][64];
    __shared__ int    bsx[256];
    __shared__ int    ws[4];
    const int t = threadIdx.x;
    const int lane = t & 63;
    const int wv   = t >> 6;

    {
        const int v = (t < SCAN_BLOCKS) ? bsum[t] : 0;
        int sc = v;
        #pragma unroll
        for (int off = 1; off < 64; off <<= 1) {
            const int n = __shfl_up(sc, off);
            if (lane >= off) sc += n;
        }
        if (lane == 63) ws[wv] = sc;
        __syncthreads();
        int prefix = 0;
        for (int j = 0; j < wv; ++j) prefix += ws[j];
        bsx[t] = prefix + sc - v;
        __syncthreads();
    }

    const int d = blockIdx.x * 4 + wv;                   // 12500*4 = 50000
    const int row = lscan[d] + bsx[d >> 8];
    const int deg = cnt[d];
    const float4 ad = *reinterpret_cast<const float4*>(adst + (size_t)d * 4);
    const char* xwB = (const char*)xw2;
    const int laneB = lane << 3;

    float dn0 = 0.f, dn1 = 0.f, dn2 = 0.f, dn3 = 0.f;
    float ac0 = 0.f, ac1 = 0.f, ac2 = 0.f, ac3 = 0.f;

    for (int base = 0; base < deg; base += 64) {
        const int m = min(64, deg - base);
        if (lane < m) {
            const int s = esrc[row + base + lane];
            const float4 as = *reinterpret_cast<const float4*>(asrc + (size_t)s * 4);
            const float e0 = __expf(lrelu(as.x + ad.x));
            const float e1 = __expf(lrelu(as.y + ad.y));
            const float e2 = __expf(lrelu(as.z + ad.z));
            const float e3 = __expf(lrelu(as.w + ad.w));
            dn0 += e0; dn1 += e1; dn2 += e2; dn3 += e3;
            wbuf[wv][lane] = make_float4(e0, e1, e2, e3);
            sbuf[wv][lane] = s << 9;   // *512 B node row
        }
        int j = 0;
        for (; j + 4 <= m; j += 4) {
            uint2 v0 = *(const uint2*)(xwB + sbuf[wv][j]     + laneB);
            uint2 v1 = *(const uint2*)(xwB + sbuf[wv][j + 1] + laneB);
            uint2 v2 = *(const uint2*)(xwB + sbuf[wv][j + 2] + laneB);
            uint2 v3 = *(const uint2*)(xwB + sbuf[wv][j + 3] + laneB);
            {
                const float4 w = wbuf[wv][j];
                ac0 = fmaf(w.x, bflo(v0.x), ac0); ac1 = fmaf(w.y, bfhi(v0.x), ac1);
                ac2 = fmaf(w.z, bflo(v0.y), ac2); ac3 = fmaf(w.w, bfhi(v0.y), ac3);
            }
            {
                const float4 w = wbuf[wv][j + 1];
                ac0 = fmaf(w.x, bflo(v1.x), ac0); ac1 = fmaf(w.y, bfhi(v1.x), ac1);
                ac2 = fmaf(w.z, bflo(v1.y), ac2); ac3 = fmaf(w.w, bfhi(v1.y), ac3);
            }
            {
                const float4 w = wbuf[wv][j + 2];
                ac0 = fmaf(w.x, bflo(v2.x), ac0); ac1 = fmaf(w.y, bfhi(v2.x), ac1);
                ac2 = fmaf(w.z, bflo(v2.y), ac2); ac3 = fmaf(w.w, bfhi(v2.y), ac3);
            }
            {
                const float4 w = wbuf[wv][j + 3];
                ac0 = fmaf(w.x, bflo(v3.x), ac0); ac1 = fmaf(w.y, bfhi(v3.x), ac1);
                ac2 = fmaf(w.z, bflo(v3.y), ac2); ac3 = fmaf(w.w, bfhi(v3.y), ac3);
            }
        }
        for (; j < m; ++j) {
            const float4 w = wbuf[wv][j];
            const uint2 v = *(const uint2*)(xwB + sbuf[wv][j] + laneB);
            ac0 = fmaf(w.x, bflo(v.x), ac0);
            ac1 = fmaf(w.y, bfhi(v.x), ac1);
            ac2 = fmaf(w.z, bflo(v.y), ac2);
            ac3 = fmaf(w.w, bfhi(v.y), ac3);
        }
    }

    #pragma unroll
    for (int off = 32; off >= 1; off >>= 1) {
        dn0 += __shfl_xor(dn0, off);
        dn1 += __shfl_xor(dn1, off);
        dn2 += __shfl_xor(dn2, off);
        dn3 += __shfl_xor(dn3, off);
    }
    // self-loop
    const float4 asd = *reinterpret_cast<const float4*>(asrc + (size_t)d * 4);
    const float s0 = __expf(lrelu(asd.x + ad.x));
    const float s1 = __expf(lrelu(asd.y + ad.y));
    const float s2 = __expf(lrelu(asd.z + ad.z));
    const float s3 = __expf(lrelu(asd.w + ad.w));
    const uint2 u = xw2[(size_t)d * 64 + lane];
    ac0 = fmaf(s0, bflo(u.x), ac0); ac1 = fmaf(s1, bfhi(u.x), ac1);
    ac2 = fmaf(s2, bflo(u.y), ac2); ac3 = fmaf(s3, bfhi(u.y), ac3);
    const float i0 = 0.25f / (dn0 + s0);
    const float i1 = 0.25f / (dn1 + s1);
    const float i2 = 0.25f / (dn2 + s2);
    const float i3 = 0.25f / (dn3 + s3);
    const float v = ac0 * i0 + ac1 * i1 + ac2 * i2 + ac3 * i3
                  + bias[lane] + xres[(size_t)d * OUT_CH + lane];
    out[(size_t)d * OUT_CH + lane] = fmaxf(v, 0.f);
}

extern "C" void kernel_launch(void* const* d_in, const int* in_sizes, int n_in,
                              void* d_out, int out_size, void* d_ws, size_t ws_size,
                              hipStream_t stream) {
    const float* x    = (const float*)d_in[0];
    const int*   ei   = (const int*)d_in[1];
    const float* W    = (const float*)d_in[2];
    const float* attS = (const float*)d_in[3];
    const float* attD = (const float*)d_in[4];
    const float* bias = (const float*)d_in[5];
    const float* Wres = (const float*)d_in[6];
    float* out = (float*)d_out;

    char* p = (char*)d_ws;
    uint4*    Bp      = (uint4*)p;    p += (size_t)NKK * NTILES * 64 * 16;  // 160 KB
    uint2*    xw2     = (uint2*)p;    p += (size_t)N_NODES * 64 * 8;        // 25.6 MB
    float*    xres    = (float*)p;    p += (size_t)N_NODES * OUT_CH * 4;    // 12.8 MB
    float*    asrc    = (float*)p;    p += (size_t)N_NODES * HEADS * 4;
    float*    adst    = (float*)p;    p += (size_t)N_NODES * HEADS * 4;
    int*      M       = (int*)p;      p += (size_t)NBINS * P1_BLOCKS * 4;   // 400 KB
    int*      binCnt  = (int*)p;      p += 512 * 4;
    int*      binStart= (int*)p;      p += 512 * 4;
    int*      cnt     = (int*)p;      p += (size_t)N_NODES * 4;
    int*      lscan   = (int*)p;      p += (size_t)N_NODES * 4;
    int*      bsum    = (int*)p;      p += 256 * 4;
    unsigned* mid     = (unsigned*)p; p += (size_t)N_EDGES * 4;             // 3.2 MB
    int*      esrc    = (int*)p;      p += (size_t)N_EDGES * 4;             // 3.2 MB

    pack_B<<<PACK_BLOCKS, 256, 0, stream>>>(W, Wres, Bp);
    gemm_hist<<<GEMM_BLOCKS + P1_BLOCKS, 256, 0, stream>>>(
        x, Bp, xw2, xres, ei, M, attS, attD, asrc, adst);
    binscan_M<<<NBINS, 256, 0, stream>>>(M, binCnt);
    binstart_scan<<<1, 512, 0, stream>>>(binCnt, binStart);
    part_mid<<<P1_BLOCKS, 256, 0, stream>>>(ei, M, binStart, mid);
    count_fine<<<NBINS, 256, 0, stream>>>(mid, binStart, binCnt, cnt);
    scan_local<<<SCAN_BLOCKS, 256, 0, stream>>>(cnt, lscan, bsum);
    scatter_fine<<<NBINS, 256, 0, stream>>>(mid, binStart, binCnt, lscan, bsum, esrc);
    aggregate<<<AGG_BLOCKS, 256, 0, stream>>>(
        esrc, lscan, bsum, cnt, asrc, adst, xw2, xres, bias, out);
}

// Round 6
// 237.456 us; speedup vs baseline: 1.0666x; 1.0150x over previous
//
#include <hip/hip_runtime.h>
#include <math.h>

#define N_NODES 50000
#define N_EDGES 800000
#define IN_CH   256
#define OUT_CH  64
#define HEADS   4
#define NEG_SLOPE 0.2f
#define NCOLS   320           // W (256) || W_res (64)
#define NTILES  20            // NCOLS / 16
#define NKK     8             // IN_CH / 32
#define PACK_BLOCKS 40        // NKK*NTILES*64 / 256
#define GEMM_BLOCKS 782       // (N_NODES+63)/64
#define NBINS   391           // ceil(N_NODES/128): bin = dst>>7
#define P1_BLOCKS 256         // edge-partition blocks
#define EPB     3125          // edges per partition block = N_EDGES/256
#define AGG_BLOCKS 6250       // half of N_NODES/4; two dispatches (visibility:
                              // drops top-5 cutoff to ~38us so gemm_hist shows)
#define STASH_CAP 2816        // max edges per bin (mean 2048, sd ~45) + margin

typedef __attribute__((ext_vector_type(8))) short short8;
typedef __attribute__((ext_vector_type(4))) float f32x4;

__device__ __forceinline__ float lrelu(float v) {
    return v > 0.f ? v : NEG_SLOPE * v;
}
__device__ __forceinline__ unsigned bf16_rne(float f) {
    unsigned u = __float_as_uint(f);
    return (u + 0x7FFFu + ((u >> 16) & 1u)) >> 16;
}
__device__ __forceinline__ unsigned pack2(float lo, float hi) {
    return bf16_rne(lo) | (bf16_rne(hi) << 16);
}
__device__ __forceinline__ float bflo(unsigned u) { return __uint_as_float(u << 16); }
__device__ __forceinline__ float bfhi(unsigned u) { return __uint_as_float(u & 0xFFFF0000u); }
__device__ __forceinline__ short8 as_short8(uint4 u) {
    union { uint4 u4; short8 s8; } cv; cv.u4 = u; return cv.s8;
}

// ---------------------------------------------------------------------------
// pack_B: [W | W_res] fp32 -> bf16 MFMA B-fragment order (tiny, 40 blocks).
// ---------------------------------------------------------------------------
__global__ __launch_bounds__(256) void pack_B(
    const float* __restrict__ W, const float* __restrict__ Wres,
    uint4* __restrict__ Bp)
{
    const int idx  = blockIdx.x * 256 + threadIdx.x;   // 0..10239
    const int kk   = idx / (NTILES * 64);
    const int rem  = idx - kk * (NTILES * 64);
    const int t    = rem >> 6;
    const int lane = rem & 63;
    const int colL = lane & 15, quad = lane >> 4;
    const int col  = t * 16 + colL;
    const int k0   = kk * 32 + quad * 8;
    float v[8];
    #pragma unroll
    for (int j = 0; j < 8; ++j) {
        const int k = k0 + j;
        v[j] = (col < IN_CH) ? W[(size_t)k * IN_CH + col]
                             : Wres[(size_t)k * OUT_CH + (col - IN_CH)];
    }
    uint4 u;
    u.x = pack2(v[0], v[1]); u.y = pack2(v[2], v[3]);
    u.z = pack2(v[4], v[5]); u.w = pack2(v[6], v[7]);
    Bp[(kk * NTILES + t) * 64 + lane] = u;
}

// ---------------------------------------------------------------------------
// gemm_hist: fused independent halves.
//   blocks [0, GEMM_BLOCKS)          : MFMA node transform + FUSED LOGITS
//   blocks [GEMM_BLOCKS,+P1_BLOCKS)  : coarse partition histogram (R5;
//     atomic-free CSR build — LDS histogram into 391 bins -> M[bin][block]).
// ---------------------------------------------------------------------------
__global__ __launch_bounds__(256) void gemm_hist(
    const float* __restrict__ x, const uint4* __restrict__ Bp,
    uint2* __restrict__ xw2, float* __restrict__ xres,
    const int* __restrict__ ei, int* __restrict__ M,
    const float* __restrict__ attS, const float* __restrict__ attD,
    float* __restrict__ asrc, float* __restrict__ adst)
{
    __shared__ uint4 Alds[4 * NKK * 64];   // 32 KB
    __shared__ float logS[64][HEADS];      // 1 KB
    __shared__ float logD[64][HEADS];      // 1 KB

    if (blockIdx.x >= GEMM_BLOCKS) {
        const int blk = blockIdx.x - GEMM_BLOCKS;      // 0..255
        int* lh = (int*)Alds;                          // reuse 32 KB LDS
        for (int b = threadIdx.x; b < NBINS; b += 256) lh[b] = 0;
        __syncthreads();
        const int e0 = blk * EPB;
        #pragma unroll
        for (int r = 0; r < 13; ++r) {
            const int idx = (r << 8) + threadIdx.x;
            if (idx < EPB)
                atomicAdd(&lh[ei[N_EDGES + e0 + idx] >> 7], 1);
        }
        __syncthreads();
        for (int b = threadIdx.x; b < NBINS; b += 256)
            M[(size_t)b * P1_BLOCKS + blk] = lh[b];
        return;
    }

    const int tid = threadIdx.x;
    const int n0  = blockIdx.x * 64;

    logS[tid >> 2][tid & 3] = 0.f;
    logD[tid >> 2][tid & 3] = 0.f;

    #pragma unroll
    for (int i = 0; i < 8; ++i) {
        const int e    = i * 256 + tid;
        const int g    = e >> 9;
        const int kk   = (e >> 6) & 7;
        const int lane = e & 63;
        const int cL   = lane & 15, qd = lane >> 4;
        const int row  = n0 + g * 16 + cL;
        const int k0   = kk * 32 + qd * 8;
        uint4 u = make_uint4(0u, 0u, 0u, 0u);
        if (row < N_NODES) {
            const float4 a = *reinterpret_cast<const float4*>(x + (size_t)row * IN_CH + k0);
            const float4 b = *reinterpret_cast<const float4*>(x + (size_t)row * IN_CH + k0 + 4);
            u.x = pack2(a.x, a.y); u.y = pack2(a.z, a.w);
            u.z = pack2(b.x, b.y); u.w = pack2(b.z, b.w);
        }
        Alds[(g * NKK + kk) * 64 + lane] = u;
    }
    __syncthreads();

    const int lane = tid & 63;
    const int wv   = tid >> 6;
    const int colL = lane & 15, quad = lane >> 4;

    f32x4 acc[4][5];
    #pragma unroll
    for (int rg = 0; rg < 4; ++rg)
        #pragma unroll
        for (int j = 0; j < 5; ++j) acc[rg][j] = (f32x4){0.f, 0.f, 0.f, 0.f};

    for (int kk = 0; kk < NKK; ++kk) {
        uint4 bu[5];
        #pragma unroll
        for (int j = 0; j < 5; ++j)
            bu[j] = Bp[(kk * NTILES + j * 4 + wv) * 64 + lane];
        #pragma unroll
        for (int rg = 0; rg < 4; ++rg) {
            const short8 a = as_short8(Alds[(rg * NKK + kk) * 64 + lane]);
            #pragma unroll
            for (int j = 0; j < 5; ++j)
                acc[rg][j] = __builtin_amdgcn_mfma_f32_16x16x32_bf16(
                    a, as_short8(bu[j]), acc[rg][j], 0, 0, 0);
        }
    }

    // ---- store xw2 / xres ----
    #pragma unroll
    for (int rg = 0; rg < 4; ++rg) {
        #pragma unroll
        for (int r = 0; r < 4; ++r) {
            const int row = n0 + rg * 16 + quad * 4 + r;
            if (row < N_NODES) {
                xw2[(size_t)row * 64 + wv * 16 + colL] = make_uint2(
                    pack2(acc[rg][0][r], acc[rg][1][r]),
                    pack2(acc[rg][2][r], acc[rg][3][r]));
                xres[(size_t)row * OUT_CH + wv * 16 + colL] = acc[rg][4][r];
            }
        }
    }

    // ---- fused logits ----
    float aSr[HEADS], aDr[HEADS];
    #pragma unroll
    for (int h = 0; h < HEADS; ++h) {
        aSr[h] = attS[h * 64 + wv * 16 + colL];
        aDr[h] = attD[h * 64 + wv * 16 + colL];
    }
    #pragma unroll
    for (int rg = 0; rg < 4; ++rg) {
        #pragma unroll
        for (int h = 0; h < HEADS; ++h) {
            #pragma unroll
            for (int r = 0; r < 4; ++r) {
                float vS = acc[rg][h][r] * aSr[h];
                float vD = acc[rg][h][r] * aDr[h];
                #pragma unroll
                for (int m = 1; m < 16; m <<= 1) {      // stays within quad
                    vS += __shfl_xor(vS, m);
                    vD += __shfl_xor(vD, m);
                }
                if (colL == 0) {
                    atomicAdd(&logS[rg * 16 + quad * 4 + r][h], vS);
                    atomicAdd(&logD[rg * 16 + quad * 4 + r][h], vD);
                }
            }
        }
    }
    __syncthreads();
    {
        const int rl = tid >> 2, h = tid & 3;
        const int row = n0 + rl;
        if (row < N_NODES) {
            asrc[(size_t)row * HEADS + h] = logS[rl][h];
            adst[(size_t)row * HEADS + h] = logD[rl][h];
        }
    }
}

// ---------------------------------------------------------------------------
// binscan_M: one block per bin; exclusive-scan M[b][0..255] in place,
// total -> binCnt[b].
// ---------------------------------------------------------------------------
__global__ __launch_bounds__(256) void binscan_M(
    int* __restrict__ M, int* __restrict__ binCnt)
{
    __shared__ int ws[4];
    const int t = threadIdx.x, lane = t & 63, w = t >> 6;
    const int b = blockIdx.x;
    const int v = M[(size_t)b * P1_BLOCKS + t];
    int sc = v;
    #pragma unroll
    for (int off = 1; off < 64; off <<= 1) {
        const int n = __shfl_up(sc, off);
        if (lane >= off) sc += n;
    }
    if (lane == 63) ws[w] = sc;
    __syncthreads();
    int prefix = 0;
    for (int j = 0; j < w; ++j) prefix += ws[j];
    M[(size_t)b * P1_BLOCKS + t] = prefix + sc - v;
    if (t == 255) binCnt[b] = prefix + sc;
}

// ---------------------------------------------------------------------------
// part_mid: 256 blocks; INLINE 391-wide binStart scan from binCnt (L2-hot,
// ~free — replaces the old 1-block binstart_scan launch), then re-read own
// edge chunk, LDS running positions per bin, write bin-major records
// mid = (dst&127)<<17 | src. No global atomics.
// ---------------------------------------------------------------------------
__global__ __launch_bounds__(256) void part_mid(
    const int* __restrict__ ei, const int* __restrict__ M,
    const int* __restrict__ binCnt, unsigned* __restrict__ mid)
{
    __shared__ int bc[NBINS];
    __shared__ int bs[NBINS];
    __shared__ int baseL[NBINS];
    __shared__ int lh[NBINS];
    __shared__ int ws[4];
    const int t = threadIdx.x, lane = t & 63, wv = t >> 6;
    const int blk = blockIdx.x;

    for (int b = t; b < NBINS; b += 256) {
        bc[b] = binCnt[b];
        baseL[b] = M[(size_t)b * P1_BLOCKS + blk];
        lh[b] = 0;
    }
    __syncthreads();

    // exclusive scan bc[0..390] -> bs (round 0: 0..255, round 1: 256..390)
    int tot0;
    {
        const int v = bc[t];
        int sc = v;
        #pragma unroll
        for (int off = 1; off < 64; off <<= 1) {
            const int n = __shfl_up(sc, off);
            if (lane >= off) sc += n;
        }
        if (lane == 63) ws[wv] = sc;
        __syncthreads();
        int prefix = 0;
        for (int j = 0; j < wv; ++j) prefix += ws[j];
        bs[t] = prefix + sc - v;
        tot0 = ws[0] + ws[1] + ws[2] + ws[3];
        __syncthreads();   // done reading ws before round 1 rewrites it
    }
    {
        const int i2 = 256 + t;
        const int v = (i2 < NBINS) ? bc[i2] : 0;
        int sc = v;
        #pragma unroll
        for (int off = 1; off < 64; off <<= 1) {
            const int n = __shfl_up(sc, off);
            if (lane >= off) sc += n;
        }
        if (lane == 63) ws[wv] = sc;
        __syncthreads();
        int prefix = 0;
        for (int j = 0; j < wv; ++j) prefix += ws[j];
        if (i2 < NBINS) bs[i2] = tot0 + prefix + sc - v;
        __syncthreads();
    }
    for (int b = t; b < NBINS; b += 256) baseL[b] += bs[b];
    __syncthreads();

    const int e0 = blk * EPB;
    #pragma unroll
    for (int r = 0; r < 13; ++r) {
        const int idx = (r << 8) + t;
        if (idx < EPB) {
            const int e = e0 + idx;
            const int d = ei[N_EDGES + e];
            const int b = d >> 7;
            const int pos = atomicAdd(&lh[b], 1);
            mid[baseL[b] + pos] = ((unsigned)(d & 127) << 17) | (unsigned)ei[e];
        }
    }
}

// ---------------------------------------------------------------------------
// scatter_fine2 (R6): one block per bin. Fuses count_fine + scan_local +
// scatter_fine. Derives the GLOBAL CSR offsets directly from the bin
// structure: lscan[d] = binStart[b] + within-bin exclusive dst prefix —
// bins are dst-ordered, so this equals the global exclusive scan. Writes
// cnt[d], lscan[d] (for aggregate; kills bsum machinery everywhere) and
// the final esrc. Bin records stashed in LDS (one global read).
// ---------------------------------------------------------------------------
__global__ __launch_bounds__(256) void scatter_fine2(
    const unsigned* __restrict__ mid, const int* __restrict__ binCnt,
    int* __restrict__ cnt, int* __restrict__ lscan, int* __restrict__ esrc)
{
    __shared__ int ws[4];
    __shared__ int c128[128];
    __shared__ int o128[128];
    __shared__ int w0tot;
    __shared__ unsigned stash[STASH_CAP];
    const int t = threadIdx.x, lane = t & 63, wv = t >> 6;
    const int b = blockIdx.x;

    // base = sum of binCnt[j] for j < b (masked block reduce, L2-hot)
    int acc = 0;
    for (int j = t; j < NBINS; j += 256)
        if (j < b) acc += binCnt[j];
    #pragma unroll
    for (int off = 32; off >= 1; off >>= 1) acc += __shfl_xor(acc, off);
    if (lane == 0) ws[wv] = acc;
    if (t < 128) c128[t] = 0;
    __syncthreads();
    const int base = ws[0] + ws[1] + ws[2] + ws[3];
    const int n = binCnt[b];

    // count (+ stash records in LDS)
    for (int i = t; i < n; i += 256) {
        const unsigned m = mid[base + i];
        if (i < STASH_CAP) stash[i] = m;
        atomicAdd(&c128[m >> 17], 1);
    }
    __syncthreads();

    // 128-wide exclusive scan of c128 -> o128; write cnt/lscan
    if (t < 128) {
        const int v = c128[t];
        int sc = v;
        #pragma unroll
        for (int off = 1; off < 64; off <<= 1) {
            const int nn = __shfl_up(sc, off);
            if (lane >= off) sc += nn;
        }
        if (t == 63) w0tot = sc;
        __syncthreads();
        const int ex = sc - v + (t >= 64 ? w0tot : 0);
        o128[t] = ex;
        const int d = (b << 7) + t;
        if (d < N_NODES) {
            cnt[d] = v;
            lscan[d] = base + ex;
        }
        c128[t] = 0;               // reuse as running positions
    } else {
        __syncthreads();
    }
    __syncthreads();

    // scatter
    for (int i = t; i < n; i += 256) {
        const unsigned m = (i < STASH_CAP) ? stash[i] : mid[base + i];
        const int dlo = (int)(m >> 17);
        const int pos = atomicAdd(&c128[dlo], 1);
        esrc[base + o128[dlo] + pos] = (int)(m & 0x1FFFFu);
    }
}

// ---------------------------------------------------------------------------
// aggregate, single-pass, unnormalized head accumulators. R6: reads lscan/cnt
// directly (bsum machinery gone). Per 64-edge chunk: lane-parallel gather
// asrc + exp -> LDS stash; per edge: uniform-addr LDS broadcast + ONE
// dwordx2 gather + 4 fma. R1 established this is at its structural floor:
// 214 MB = 8 XCD x 25.6 MB compulsory L2 streaming of xw2 at ~3.3 TB/s
// (request-rate/MSHR-bound; extra wave-level MLP was a measured no-op).
// Two half dispatches (measured ~free, R4<->R5) so top-5 cutoff drops to
// ~38us and gemm_hist's counters surface next round.
// ---------------------------------------------------------------------------
__global__ __launch_bounds__(256) void aggregate(
    const int* __restrict__ esrc, const int* __restrict__ lscan,
    const int* __restrict__ cnt,
    const float* __restrict__ asrc, const float* __restrict__ adst,
    const uint2* __restrict__ xw2, const float* __restrict__ xres,
    const float* __restrict__ bias, float* __restrict__ out,
    const int d0)
{
    __shared__ float4 wbuf[4][64];
    __shared__ int    sbuf[4][64];
    const int t = threadIdx.x;
    const int lane = t & 63;
    const int wv   = t >> 6;

    const int d = d0 + blockIdx.x * 4 + wv;
    const int row = lscan[d];
    const int deg = cnt[d];
    const float4 ad = *reinterpret_cast<const float4*>(adst + (size_t)d * 4);
    const char* xwB = (const char*)xw2;
    const int laneB = lane << 3;

    float dn0 = 0.f, dn1 = 0.f, dn2 = 0.f, dn3 = 0.f;
    float ac0 = 0.f, ac1 = 0.f, ac2 = 0.f, ac3 = 0.f;

    for (int base = 0; base < deg; base += 64) {
        const int m = min(64, deg - base);
        if (lane < m) {
            const int s = esrc[row + base + lane];
            const float4 as = *reinterpret_cast<const float4*>(asrc + (size_t)s * 4);
            const float e0 = __expf(lrelu(as.x + ad.x));
            const float e1 = __expf(lrelu(as.y + ad.y));
            const float e2 = __expf(lrelu(as.z + ad.z));
            const float e3 = __expf(lrelu(as.w + ad.w));
            dn0 += e0; dn1 += e1; dn2 += e2; dn3 += e3;
            wbuf[wv][lane] = make_float4(e0, e1, e2, e3);
            sbuf[wv][lane] = s << 9;   // *512 B node row
        }
        int j = 0;
        for (; j + 4 <= m; j += 4) {
            uint2 v0 = *(const uint2*)(xwB + sbuf[wv][j]     + laneB);
            uint2 v1 = *(const uint2*)(xwB + sbuf[wv][j + 1] + laneB);
            uint2 v2 = *(const uint2*)(xwB + sbuf[wv][j + 2] + laneB);
            uint2 v3 = *(const uint2*)(xwB + sbuf[wv][j + 3] + laneB);
            {
                const float4 w = wbuf[wv][j];
                ac0 = fmaf(w.x, bflo(v0.x), ac0); ac1 = fmaf(w.y, bfhi(v0.x), ac1);
                ac2 = fmaf(w.z, bflo(v0.y), ac2); ac3 = fmaf(w.w, bfhi(v0.y), ac3);
            }
            {
                const float4 w = wbuf[wv][j + 1];
                ac0 = fmaf(w.x, bflo(v1.x), ac0); ac1 = fmaf(w.y, bfhi(v1.x), ac1);
                ac2 = fmaf(w.z, bflo(v1.y), ac2); ac3 = fmaf(w.w, bfhi(v1.y), ac3);
            }
            {
                const float4 w = wbuf[wv][j + 2];
                ac0 = fmaf(w.x, bflo(v2.x), ac0); ac1 = fmaf(w.y, bfhi(v2.x), ac1);
                ac2 = fmaf(w.z, bflo(v2.y), ac2); ac3 = fmaf(w.w, bfhi(v2.y), ac3);
            }
            {
                const float4 w = wbuf[wv][j + 3];
                ac0 = fmaf(w.x, bflo(v3.x), ac0); ac1 = fmaf(w.y, bfhi(v3.x), ac1);
                ac2 = fmaf(w.z, bflo(v3.y), ac2); ac3 = fmaf(w.w, bfhi(v3.y), ac3);
            }
        }
        for (; j < m; ++j) {
            const float4 w = wbuf[wv][j];
            const uint2 v = *(const uint2*)(xwB + sbuf[wv][j] + laneB);
            ac0 = fmaf(w.x, bflo(v.x), ac0);
            ac1 = fmaf(w.y, bfhi(v.x), ac1);
            ac2 = fmaf(w.z, bflo(v.y), ac2);
            ac3 = fmaf(w.w, bfhi(v.y), ac3);
        }
    }

    #pragma unroll
    for (int off = 32; off >= 1; off >>= 1) {
        dn0 += __shfl_xor(dn0, off);
        dn1 += __shfl_xor(dn1, off);
        dn2 += __shfl_xor(dn2, off);
        dn3 += __shfl_xor(dn3, off);
    }
    // self-loop
    const float4 asd = *reinterpret_cast<const float4*>(asrc + (size_t)d * 4);
    const float s0 = __expf(lrelu(asd.x + ad.x));
    const float s1 = __expf(lrelu(asd.y + ad.y));
    const float s2 = __expf(lrelu(asd.z + ad.z));
    const float s3 = __expf(lrelu(asd.w + ad.w));
    const uint2 u = xw2[(size_t)d * 64 + lane];
    ac0 = fmaf(s0, bflo(u.x), ac0); ac1 = fmaf(s1, bfhi(u.x), ac1);
    ac2 = fmaf(s2, bflo(u.y), ac2); ac3 = fmaf(s3, bfhi(u.y), ac3);
    const float i0 = 0.25f / (dn0 + s0);
    const float i1 = 0.25f / (dn1 + s1);
    const float i2 = 0.25f / (dn2 + s2);
    const float i3 = 0.25f / (dn3 + s3);
    const float v = ac0 * i0 + ac1 * i1 + ac2 * i2 + ac3 * i3
                  + bias[lane] + xres[(size_t)d * OUT_CH + lane];
    out[(size_t)d * OUT_CH + lane] = fmaxf(v, 0.f);
}

extern "C" void kernel_launch(void* const* d_in, const int* in_sizes, int n_in,
                              void* d_out, int out_size, void* d_ws, size_t ws_size,
                              hipStream_t stream) {
    const float* x    = (const float*)d_in[0];
    const int*   ei   = (const int*)d_in[1];
    const float* W    = (const float*)d_in[2];
    const float* attS = (const float*)d_in[3];
    const float* attD = (const float*)d_in[4];
    const float* bias = (const float*)d_in[5];
    const float* Wres = (const float*)d_in[6];
    float* out = (float*)d_out;

    char* p = (char*)d_ws;
    uint4*    Bp      = (uint4*)p;    p += (size_t)NKK * NTILES * 64 * 16;  // 160 KB
    uint2*    xw2     = (uint2*)p;    p += (size_t)N_NODES * 64 * 8;        // 25.6 MB
    float*    xres    = (float*)p;    p += (size_t)N_NODES * OUT_CH * 4;    // 12.8 MB
    float*    asrc    = (float*)p;    p += (size_t)N_NODES * HEADS * 4;
    float*    adst    = (float*)p;    p += (size_t)N_NODES * HEADS * 4;
    int*      M       = (int*)p;      p += (size_t)NBINS * P1_BLOCKS * 4;   // 400 KB
    int*      binCnt  = (int*)p;      p += 512 * 4;
    int*      cnt     = (int*)p;      p += (size_t)N_NODES * 4;
    int*      lscan   = (int*)p;      p += (size_t)N_NODES * 4;
    unsigned* mid     = (unsigned*)p; p += (size_t)N_EDGES * 4;             // 3.2 MB
    int*      esrc    = (int*)p;      p += (size_t)N_EDGES * 4;             // 3.2 MB

    pack_B<<<PACK_BLOCKS, 256, 0, stream>>>(W, Wres, Bp);
    gemm_hist<<<GEMM_BLOCKS + P1_BLOCKS, 256, 0, stream>>>(
        x, Bp, xw2, xres, ei, M, attS, attD, asrc, adst);
    binscan_M<<<NBINS, 256, 0, stream>>>(M, binCnt);
    part_mid<<<P1_BLOCKS, 256, 0, stream>>>(ei, M, binCnt, mid);
    scatter_fine2<<<NBINS, 256, 0, stream>>>(mid, binCnt, cnt, lscan, esrc);
    aggregate<<<AGG_BLOCKS, 256, 0, stream>>>(
        esrc, lscan, cnt, asrc, adst, xw2, xres, bias, out, 0);
    aggregate<<<AGG_BLOCKS, 256, 0, stream>>>(
        esrc, lscan, cnt, asrc, adst, xw2, xres, bias, out, 25000);
}